// Round 1
// baseline (382.941 us; speedup 1.0000x reference)
//
#include <hip/hip_runtime.h>
#include <math.h>

typedef unsigned short u16;
typedef unsigned int u32;
typedef unsigned long long u64;
typedef short bf16x8 __attribute__((ext_vector_type(8)));
typedef float f32x4 __attribute__((ext_vector_type(4)));

constexpr int NB = 2, NS = 2048, ND = 512, NH = 8, NHD = 64;
constexpr int NKTOP = 307, NHWIN = 16, NRC = 16;
constexpr int LDSPAD = 40;  // 80B row stride: breaks power-of-2 LDS bank pattern, keeps 16B alignment

__device__ __forceinline__ u16 f2bf(float f) {
  u32 u = __builtin_bit_cast(u32, f);
  u32 r = (u + 0x7FFFu + ((u >> 16) & 1u)) >> 16;  // round-to-nearest-even
  return (u16)r;
}

// ---------------- convert x (fp32 -> bf16) ----------------
__global__ __launch_bounds__(256) void csa_cvt_x(const float* __restrict__ x, u16* __restrict__ xb) {
  int i = (blockIdx.x * 256 + threadIdx.x) * 4;
  float4 v = *(const float4*)(x + i);
  u32 o0 = (u32)f2bf(v.x) | ((u32)f2bf(v.y) << 16);
  u32 o1 = (u32)f2bf(v.z) | ((u32)f2bf(v.w) << 16);
  *(uint2*)(xb + i) = make_uint2(o0, o1);
}

// -------- transpose + convert weights: W[K][N] fp32 -> Wt[N][K] bf16 (4 weights) --------
__global__ __launch_bounds__(256) void csa_cvt_w(const float* __restrict__ W0, const float* __restrict__ W1,
                                                 const float* __restrict__ W2, const float* __restrict__ W3,
                                                 u16* __restrict__ wt) {
  __shared__ float tile[32][33];
  int w = blockIdx.z;
  const float* src = (w == 0) ? W0 : (w == 1) ? W1 : (w == 2) ? W2 : W3;
  int kb = blockIdx.x * 32, nb = blockIdx.y * 32;
  int tx = threadIdx.x & 31, ty = threadIdx.x >> 5;
  for (int i = ty; i < 32; i += 8) tile[i][tx] = src[(size_t)(kb + i) * ND + nb + tx];
  __syncthreads();
  u16* dst = wt + (size_t)w * ND * ND;
  for (int i = ty; i < 32; i += 8) dst[(size_t)(nb + i) * ND + kb + tx] = f2bf(tile[tx][i]);
}

// -------- scorer SGEMM (fp32!): H = relu(x @ Ws1 + bs1), M=4096 N=256 K=512 --------
__global__ __launch_bounds__(256) void csa_scorer_gemm(const float* __restrict__ A, const float* __restrict__ Bw,
                                                       const float* __restrict__ bias, float* __restrict__ Hout) {
  __shared__ float As[16][64];  // transposed A tile
  __shared__ float Bs[16][64];
  const int tid = threadIdx.x;
  const int m0 = blockIdx.x * 64;
  const int n0 = blockIdx.y * 64;
  const int ty = tid >> 4, tx = tid & 15;
  float acc[4][4] = {};
  const int lrow = tid & 63, lkq = (tid >> 6) * 4;
  const int lkk = tid >> 4, lc4 = (tid & 15) * 4;
  for (int k0 = 0; k0 < ND; k0 += 16) {
    __syncthreads();
    float4 a = *(const float4*)(&A[(size_t)(m0 + lrow) * ND + k0 + lkq]);
    As[lkq + 0][lrow] = a.x; As[lkq + 1][lrow] = a.y; As[lkq + 2][lrow] = a.z; As[lkq + 3][lrow] = a.w;
    *(float4*)(&Bs[lkk][lc4]) = *(const float4*)(&Bw[(size_t)(k0 + lkk) * 256 + n0 + lc4]);
    __syncthreads();
    for (int k = 0; k < 16; k++) {
      float4 av = *(const float4*)(&As[k][ty * 4]);
      float4 bv = *(const float4*)(&Bs[k][tx * 4]);
      float aa[4] = {av.x, av.y, av.z, av.w};
      float bb[4] = {bv.x, bv.y, bv.z, bv.w};
      for (int i = 0; i < 4; i++)
        for (int j = 0; j < 4; j++)
          acc[i][j] += aa[i] * bb[j];
    }
  }
  for (int i = 0; i < 4; i++) {
    int m = m0 + ty * 4 + i;
    for (int j = 0; j < 4; j++) {
      int n = n0 + tx * 4 + j;
      Hout[(size_t)m * 256 + n] = fmaxf(acc[i][j] + bias[n], 0.f);
    }
  }
}

// -------- logit + sigmoid: imp[row] = sigmoid(H[row,:] . Ws2 + bs2) --------
__global__ __launch_bounds__(256) void csa_logit(const float* __restrict__ Hout, const float* __restrict__ Ws2,
                                                 const float* __restrict__ bs2, float* __restrict__ imp) {
  __shared__ float red[256];
  int row = blockIdx.x, j = threadIdx.x;
  red[j] = Hout[(size_t)row * 256 + j] * Ws2[j];
  __syncthreads();
  for (int s = 128; s > 0; s >>= 1) {
    if (j < s) red[j] += red[j + s];
    __syncthreads();
  }
  if (j == 0) imp[row] = 1.f / (1.f + __expf(-(red[0] + bs2[0])));
}

// -------- exact top-k selection (matches lax.top_k tie semantics: lower index wins) --------
__global__ __launch_bounds__(256) void csa_rank(const float* __restrict__ imp, int* __restrict__ rowimp) {
  __shared__ float vals[NS];
  int b = blockIdx.y;
  for (int s = threadIdx.x; s < NS; s += 256) vals[s] = imp[b * NS + s];
  __syncthreads();
  int s = blockIdx.x * 256 + threadIdx.x;
  float v = vals[s];
  int rank = 0;
  for (int t = 0; t < NS; t++) {
    float u = vals[t];
    rank += (int)((u > v) | ((u == v) & (t < s)));
  }
  rowimp[b * NS + s] = (rank < NKTOP) ? 1 : 0;
}

// -------- random-link bitmask: rmask[b][i] is a 2048-bit set of allowed j --------
__global__ __launch_bounds__(256) void csa_randmask(const int* __restrict__ rand_idx, u64* __restrict__ rmask) {
  int tid = blockIdx.x * 256 + threadIdx.x;  // grid sized exactly B*S*RC
  int j = rand_idx[tid];
  int bi = tid / NRC;  // flat b*NS + i
  atomicOr(&rmask[(size_t)bi * 32 + (j >> 6)], 1ull << (j & 63));
}

// -------- bf16 MFMA GEMM, Bt = W^T [N][K] input. mode: 0=Q 1=K 2=Vt 3=final fp32 out --------
__global__ __launch_bounds__(256) void csa_gemm_bt(const u16* __restrict__ A, const u16* __restrict__ Bt,
                                                   const float* __restrict__ bias, void* __restrict__ outp,
                                                   const int mode) {
  __shared__ __attribute__((aligned(16))) u16 As[64 * LDSPAD];
  __shared__ __attribute__((aligned(16))) u16 Bs[64 * LDSPAD];
  const int tid = threadIdx.x;
  const int wave = tid >> 6;
  const int lane = tid & 63;
  const int quad = lane >> 4;
  const int col = lane & 15;
  const int m0 = blockIdx.x * 64;
  const int n0 = blockIdx.y * 64;
  const f32x4 zf = {0.f, 0.f, 0.f, 0.f};
  f32x4 acc[4] = {zf, zf, zf, zf};
  const int lrow = tid >> 2;
  const int lk = (tid & 3) * 8;
  for (int k0 = 0; k0 < ND; k0 += 32) {
    __syncthreads();
    *(uint4*)(&As[lrow * LDSPAD + lk]) = *(const uint4*)(&A[(size_t)(m0 + lrow) * ND + k0 + lk]);
    *(uint4*)(&Bs[lrow * LDSPAD + lk]) = *(const uint4*)(&Bt[(size_t)(n0 + lrow) * ND + k0 + lk]);
    __syncthreads();
    bf16x8 af = *(const bf16x8*)(&As[(wave * 16 + col) * LDSPAD + quad * 8]);
    for (int nt = 0; nt < 4; nt++) {
      bf16x8 bf = *(const bf16x8*)(&Bs[(nt * 16 + col) * LDSPAD + quad * 8]);
      acc[nt] = __builtin_amdgcn_mfma_f32_16x16x32_bf16(af, bf, acc[nt], 0, 0, 0);
    }
  }
  for (int nt = 0; nt < 4; nt++) {
    const int n = n0 + nt * 16 + col;
    const float bv = bias[n];
    for (int r = 0; r < 4; r++) {
      const int m = m0 + wave * 16 + quad * 4 + r;
      float v = acc[nt][r] + bv;
      if (mode == 3) {
        ((float*)outp)[(size_t)m * ND + n] = v;
      } else {
        const int bb = m >> 11, s = m & (NS - 1);
        const int hh = n >> 6, hd = n & (NHD - 1);
        if (mode == 2)
          ((u16*)outp)[((size_t)(bb * NH + hh) * NHD + hd) * NS + s] = f2bf(v);  // V transposed [B,H,HD,S]
        else
          ((u16*)outp)[((size_t)(bb * NH + hh) * NS + s) * NHD + hd] = f2bf(v);  // [B,H,S,HD]
      }
    }
  }
}

// -------- masked flash attention: 1 wave per 16 q-rows, 32-key tiles --------
__global__ __launch_bounds__(64) void csa_attn(const u16* __restrict__ qb, const u16* __restrict__ kb,
                                               const u16* __restrict__ vtb, const int* __restrict__ rowimp,
                                               const u64* __restrict__ rmask, u16* __restrict__ attn) {
  const int lane = threadIdx.x;
  const int quad = lane >> 4;
  const int col = lane & 15;
  const int q0 = blockIdx.x * 16;
  const int h = blockIdx.y;
  const int b = blockIdx.z;

  const u16* qptr = qb + (size_t)(b * NH + h) * NS * NHD;
  const u16* kptr = kb + (size_t)(b * NH + h) * NS * NHD;
  const u16* vptr = vtb + (size_t)(b * NH + h) * NHD * NS;

  // Q A-fragments: A[m=col][k=quad*8+j], two K=32 steps over HD=64
  bf16x8 qf0 = *(const bf16x8*)(qptr + (q0 + col) * NHD + quad * 8);
  bf16x8 qf1 = *(const bf16x8*)(qptr + (q0 + col) * NHD + 32 + quad * 8);

  const f32x4 zf = {0.f, 0.f, 0.f, 0.f};
  float m_r[4], l_r[4];
  f32x4 of[4];  // O accumulator, rows quad*4+r, hd cols vn*16+col
  int impf[4], irow[4];
  const u64* rmrow[4];
  for (int r = 0; r < 4; r++) {
    m_r[r] = -INFINITY;
    l_r[r] = 0.f;
    irow[r] = q0 + quad * 4 + r;
    impf[r] = rowimp[b * NS + irow[r]];
    rmrow[r] = rmask + (size_t)(b * NS + irow[r]) * 32;
  }
  for (int n = 0; n < 4; n++) of[n] = zf;

  __shared__ __attribute__((aligned(16))) u16 Pl[16 * LDSPAD];

  const int ntiles = (q0 + 16 + 31) >> 5;  // keys processed: [0, ntiles*32) <= S
  for (int t = 0; t < ntiles; t++) {
    const int j0 = t * 32;
    // scores S = Q K^T : two 16-col key tiles
    f32x4 c0 = zf, c1 = zf;
    {
      bf16x8 k00 = *(const bf16x8*)(kptr + (j0 + col) * NHD + quad * 8);
      bf16x8 k01 = *(const bf16x8*)(kptr + (j0 + col) * NHD + 32 + quad * 8);
      c0 = __builtin_amdgcn_mfma_f32_16x16x32_bf16(qf0, k00, c0, 0, 0, 0);
      c0 = __builtin_amdgcn_mfma_f32_16x16x32_bf16(qf1, k01, c0, 0, 0, 0);
      bf16x8 k10 = *(const bf16x8*)(kptr + (j0 + 16 + col) * NHD + quad * 8);
      bf16x8 k11 = *(const bf16x8*)(kptr + (j0 + 16 + col) * NHD + 32 + quad * 8);
      c1 = __builtin_amdgcn_mfma_f32_16x16x32_bf16(qf0, k10, c1, 0, 0, 0);
      c1 = __builtin_amdgcn_mfma_f32_16x16x32_bf16(qf1, k11, c1, 0, 0, 0);
    }
    const int j_0 = j0 + col, j_1 = j0 + 16 + col;
    float p0s[4], p1s[4], alpha[4];
    for (int r = 0; r < 4; r++) {
      const int i = irow[r];
      const u64 rw = rmrow[r][j0 >> 6];  // one 64-bit word covers both 16-key halves (j0 % 64 in {0,32})
      float s0 = c0[r] * 0.125f;
      float s1 = c1[r] * 0.125f;
      bool a0 = (j_0 <= i) && (impf[r] || (i - j_0 <= NHWIN) || ((rw >> (j_0 & 63)) & 1));
      bool a1 = (j_1 <= i) && (impf[r] || (i - j_1 <= NHWIN) || ((rw >> (j_1 & 63)) & 1));
      s0 = a0 ? s0 : -INFINITY;
      s1 = a1 ? s1 : -INFINITY;
      float vmax = fmaxf(s0, s1);
      for (int off = 1; off < 16; off <<= 1) vmax = fmaxf(vmax, __shfl_xor(vmax, off, 64));
      float newm = fmaxf(m_r[r], vmax);
      bool dead = (newm == -INFINITY);  // row fully masked so far: keep state, p=0
      float a = dead ? 1.f : __expf(m_r[r] - newm);
      float p0 = dead ? 0.f : __expf(s0 - newm);
      float p1 = dead ? 0.f : __expf(s1 - newm);
      float psum = p0 + p1;
      for (int off = 1; off < 16; off <<= 1) psum += __shfl_xor(psum, off, 64);
      m_r[r] = newm;
      l_r[r] = l_r[r] * a + psum;
      alpha[r] = a;
      p0s[r] = p0;
      p1s[r] = p1;
    }
    for (int n = 0; n < 4; n++)
      for (int r = 0; r < 4; r++) of[n][r] *= alpha[r];
    // P: C-layout -> LDS -> A-layout (m120-verified round trip)
    __syncthreads();
    for (int r = 0; r < 4; r++) {
      Pl[(quad * 4 + r) * LDSPAD + col] = f2bf(p0s[r]);
      Pl[(quad * 4 + r) * LDSPAD + 16 + col] = f2bf(p1s[r]);
    }
    __syncthreads();
    bf16x8 pf = *(const bf16x8*)(&Pl[col * LDSPAD + quad * 8]);
    for (int vn = 0; vn < 4; vn++) {
      // B[k=quad*8+j][n=vn*16+col] = V[j0+k][hd] read from Vt[hd][j0+k] -> contiguous 16B
      bf16x8 vf = *(const bf16x8*)(vptr + (size_t)(vn * 16 + col) * NS + j0 + quad * 8);
      of[vn] = __builtin_amdgcn_mfma_f32_16x16x32_bf16(pf, vf, of[vn], 0, 0, 0);
    }
  }
  for (int r = 0; r < 4; r++) {
    float inv = 1.f / l_r[r];  // diagonal always allowed -> l > 0
    size_t base = ((size_t)(b * NS + irow[r]) * NH + h) * NHD;
    for (int vn = 0; vn < 4; vn++)
      attn[base + vn * 16 + col] = f2bf(of[vn][r] * inv);
  }
}

extern "C" void kernel_launch(void* const* d_in, const int* in_sizes, int n_in,
                              void* d_out, int out_size, void* d_ws, size_t ws_size,
                              hipStream_t stream) {
  const float* x = (const float*)d_in[0];
  const float* Wq = (const float*)d_in[1];
  const float* bq = (const float*)d_in[2];
  const float* Wk = (const float*)d_in[3];
  const float* bk = (const float*)d_in[4];
  const float* Wv = (const float*)d_in[5];
  const float* bv = (const float*)d_in[6];
  const float* Wo = (const float*)d_in[7];
  const float* bo = (const float*)d_in[8];
  const float* Ws1 = (const float*)d_in[9];
  const float* bs1 = (const float*)d_in[10];
  const float* Ws2 = (const float*)d_in[11];
  const float* bs2 = (const float*)d_in[12];
  const int* rand_idx = (const int*)d_in[13];
  float* out = (float*)d_out;

  // workspace layout (~27 MB)
  char* p = (char*)d_ws;
  u16* xb = (u16*)p;        p += (size_t)NB * NS * ND * 2;        // x bf16 [4096,512]
  u16* wt = (u16*)p;        p += (size_t)4 * ND * ND * 2;         // Wq/Wk/Wv/Wo transposed bf16 [N][K]
  u16* qbuf = (u16*)p;      p += (size_t)NB * NH * NS * NHD * 2;  // Q [B,H,S,HD]
  u16* kbuf = (u16*)p;      p += (size_t)NB * NH * NS * NHD * 2;  // K [B,H,S,HD]
  u16* vtbuf = (u16*)p;     p += (size_t)NB * NH * NHD * NS * 2;  // V^T [B,H,HD,S]
  u16* attnb = (u16*)p;     p += (size_t)NB * NS * ND * 2;        // attention out bf16 [4096,512]
  float* hbuf = (float*)p;  p += (size_t)NB * NS * (ND / 2) * 4;  // scorer hidden [4096,256]
  float* impbuf = (float*)p; p += (size_t)NB * NS * 4;
  int* rowimp = (int*)p;    p += (size_t)NB * NS * 4;
  u64* rmask = (u64*)p;     p += (size_t)NB * NS * 32 * 8;        // 2048-bit per (b,i)

  csa_cvt_x<<<dim3(NB * NS * ND / 1024), 256, 0, stream>>>(x, xb);
  csa_cvt_w<<<dim3(16, 16, 4), 256, 0, stream>>>(Wq, Wk, Wv, Wo, wt);

  // scorer chain (fp32 for exact top-k ranking)
  csa_scorer_gemm<<<dim3(64, 4), 256, 0, stream>>>(x, Ws1, bs1, hbuf);
  csa_logit<<<dim3(NB * NS), 256, 0, stream>>>(hbuf, Ws2, bs2, impbuf);
  csa_rank<<<dim3(NS / 256, NB), 256, 0, stream>>>(impbuf, rowimp);

  (void)hipMemsetAsync(rmask, 0, (size_t)NB * NS * 32 * 8, stream);
  csa_randmask<<<dim3(NB * NS * NRC / 256), 256, 0, stream>>>(rand_idx, rmask);

  // projections
  csa_gemm_bt<<<dim3(64, 8), 256, 0, stream>>>(xb, wt + 0 * (size_t)ND * ND, bq, (void*)qbuf, 0);
  csa_gemm_bt<<<dim3(64, 8), 256, 0, stream>>>(xb, wt + 1 * (size_t)ND * ND, bk, (void*)kbuf, 1);
  csa_gemm_bt<<<dim3(64, 8), 256, 0, stream>>>(xb, wt + 2 * (size_t)ND * ND, bv, (void*)vtbuf, 2);

  csa_attn<<<dim3(NS / 16, NH, NB), 64, 0, stream>>>(qbuf, kbuf, vtbuf, rowimp, rmask, attnb);

  // output projection (fp32 out + bias)
  csa_gemm_bt<<<dim3(64, 8), 256, 0, stream>>>(attnb, wt + 3 * (size_t)ND * ND, bo, (void*)out, 3);
}

// Round 2
// 278.832 us; speedup vs baseline: 1.3734x; 1.3734x over previous
//
#include <hip/hip_runtime.h>
#include <math.h>

typedef unsigned short u16;
typedef unsigned int u32;
typedef unsigned long long u64;
typedef short bf16x8 __attribute__((ext_vector_type(8)));
typedef float f32x4 __attribute__((ext_vector_type(4)));

constexpr int NB = 2, NS = 2048, ND = 512, NH = 8, NHD = 64;
constexpr int NKTOP = 307, NHWIN = 16, NRC = 16;
constexpr int NILIST = 320;  // 20 tiles of 16 (padded with -1)
constexpr int NCHUNK = 4;    // key-split factor for important-row attention
constexpr int NKMAX = 33;    // 17 window + 16 random
constexpr int LDSPAD = 40;   // 80B row stride: breaks power-of-2 bank pattern, keeps 16B align

__device__ __forceinline__ u16 f2bf(float f) {
  u32 u = __builtin_bit_cast(u32, f);
  u32 r = (u + 0x7FFFu + ((u >> 16) & 1u)) >> 16;  // RNE
  return (u16)r;
}
__device__ __forceinline__ float bf2f(short v) {
  return __builtin_bit_cast(float, (u32)(u16)v << 16);
}

// ---------------- convert x (fp32 -> bf16) ----------------
__global__ __launch_bounds__(256) void csa_cvt_x(const float* __restrict__ x, u16* __restrict__ xb) {
  int i = (blockIdx.x * 256 + threadIdx.x) * 4;
  float4 v = *(const float4*)(x + i);
  u32 o0 = (u32)f2bf(v.x) | ((u32)f2bf(v.y) << 16);
  u32 o1 = (u32)f2bf(v.z) | ((u32)f2bf(v.w) << 16);
  *(uint2*)(xb + i) = make_uint2(o0, o1);
}

// -------- transpose + convert weights: W[K][N] fp32 -> Wt[N][K] bf16 (4 weights) --------
__global__ __launch_bounds__(256) void csa_cvt_w(const float* __restrict__ W0, const float* __restrict__ W1,
                                                 const float* __restrict__ W2, const float* __restrict__ W3,
                                                 u16* __restrict__ wt) {
  __shared__ float tile[32][33];
  int w = blockIdx.z;
  const float* src = (w == 0) ? W0 : (w == 1) ? W1 : (w == 2) ? W2 : W3;
  int kb = blockIdx.x * 32, nb = blockIdx.y * 32;
  int tx = threadIdx.x & 31, ty = threadIdx.x >> 5;
  for (int i = ty; i < 32; i += 8) tile[i][tx] = src[(size_t)(kb + i) * ND + nb + tx];
  __syncthreads();
  u16* dst = wt + (size_t)w * ND * ND;
  for (int i = ty; i < 32; i += 8) dst[(size_t)(nb + i) * ND + kb + tx] = f2bf(tile[tx][i]);
}

// -------- scorer SGEMM (fp32 for exact top-k ranking): H = relu(x @ Ws1 + bs1) --------
__global__ __launch_bounds__(256) void csa_scorer_gemm(const float* __restrict__ A, const float* __restrict__ Bw,
                                                       const float* __restrict__ bias, float* __restrict__ Hout) {
  __shared__ float As[16][64];
  __shared__ float Bs[16][64];
  const int tid = threadIdx.x;
  const int m0 = blockIdx.x * 64;
  const int n0 = blockIdx.y * 64;
  const int ty = tid >> 4, tx = tid & 15;
  float acc[4][4] = {};
  const int lrow = tid & 63, lkq = (tid >> 6) * 4;
  const int lkk = tid >> 4, lc4 = (tid & 15) * 4;
  for (int k0 = 0; k0 < ND; k0 += 16) {
    __syncthreads();
    float4 a = *(const float4*)(&A[(size_t)(m0 + lrow) * ND + k0 + lkq]);
    As[lkq + 0][lrow] = a.x; As[lkq + 1][lrow] = a.y; As[lkq + 2][lrow] = a.z; As[lkq + 3][lrow] = a.w;
    *(float4*)(&Bs[lkk][lc4]) = *(const float4*)(&Bw[(size_t)(k0 + lkk) * 256 + n0 + lc4]);
    __syncthreads();
    for (int k = 0; k < 16; k++) {
      float4 av = *(const float4*)(&As[k][ty * 4]);
      float4 bv = *(const float4*)(&Bs[k][tx * 4]);
      float aa[4] = {av.x, av.y, av.z, av.w};
      float bb[4] = {bv.x, bv.y, bv.z, bv.w};
      for (int i = 0; i < 4; i++)
        for (int j = 0; j < 4; j++)
          acc[i][j] += aa[i] * bb[j];
    }
  }
  for (int i = 0; i < 4; i++) {
    int m = m0 + ty * 4 + i;
    for (int j = 0; j < 4; j++) {
      int n = n0 + tx * 4 + j;
      Hout[(size_t)m * 256 + n] = fmaxf(acc[i][j] + bias[n], 0.f);
    }
  }
}

// -------- logit + sigmoid --------
__global__ __launch_bounds__(256) void csa_logit(const float* __restrict__ Hout, const float* __restrict__ Ws2,
                                                 const float* __restrict__ bs2, float* __restrict__ imp) {
  __shared__ float red[256];
  int row = blockIdx.x, j = threadIdx.x;
  red[j] = Hout[(size_t)row * 256 + j] * Ws2[j];
  __syncthreads();
  for (int s = 128; s > 0; s >>= 1) {
    if (j < s) red[j] += red[j + s];
    __syncthreads();
  }
  if (j == 0) imp[row] = 1.f / (1.f + __expf(-(red[0] + bs2[0])));
}

// -------- exact top-k (lax.top_k tie semantics: lower index wins) --------
__global__ __launch_bounds__(256) void csa_rank(const float* __restrict__ imp, int* __restrict__ rowimp) {
  __shared__ float vals[NS];
  int b = blockIdx.y;
  for (int s = threadIdx.x; s < NS; s += 256) vals[s] = imp[b * NS + s];
  __syncthreads();
  int s = blockIdx.x * 256 + threadIdx.x;
  float v = vals[s];
  int rank = 0;
  for (int t = 0; t < NS; t++) {
    float u = vals[t];
    rank += (int)((u > v) | ((u == v) & (t < s)));
  }
  rowimp[b * NS + s] = (rank < NKTOP) ? 1 : 0;
}

// -------- compact important rows into sorted list (exactly NKTOP per batch) --------
__global__ __launch_bounds__(256) void csa_ilist(const int* __restrict__ rowimp, int* __restrict__ ilist) {
  __shared__ int cs[256];
  int b = blockIdx.x, t = threadIdx.x;
  int flags[8], sum = 0;
  for (int k = 0; k < 8; k++) {
    flags[k] = rowimp[b * NS + t * 8 + k];
    sum += flags[k];
  }
  cs[t] = sum;
  __syncthreads();
  for (int off = 1; off < 256; off <<= 1) {
    int v = (t >= off) ? cs[t - off] : 0;
    __syncthreads();
    cs[t] += v;
    __syncthreads();
  }
  int pos = cs[t] - sum;  // exclusive prefix
  for (int k = 0; k < 8; k++)
    if (flags[k]) ilist[b * NILIST + pos++] = t * 8 + k;
  if (t < NILIST - NKTOP) ilist[b * NILIST + NKTOP + t] = -1;
}

// -------- fused QKV projection: bf16 MFMA, N=1536 over [Wq^T;Wk^T;Wv^T] --------
__global__ __launch_bounds__(256) void csa_gemm_qkv(const u16* __restrict__ A, const u16* __restrict__ Bt,
                                                    const float* __restrict__ bq, const float* __restrict__ bk,
                                                    const float* __restrict__ bv, u16* __restrict__ qb,
                                                    u16* __restrict__ kb, u16* __restrict__ vtb,
                                                    u16* __restrict__ vb) {
  __shared__ __attribute__((aligned(16))) u16 As[64 * LDSPAD];
  __shared__ __attribute__((aligned(16))) u16 Bs[64 * LDSPAD];
  const int tid = threadIdx.x;
  const int wave = tid >> 6, lane = tid & 63;
  const int quad = lane >> 4, col = lane & 15;
  const int m0 = blockIdx.x * 64;
  const int n0 = blockIdx.y * 64;
  const f32x4 zf = {0.f, 0.f, 0.f, 0.f};
  f32x4 acc[4] = {zf, zf, zf, zf};
  const int lrow = tid >> 2, lk = (tid & 3) * 8;
  for (int k0 = 0; k0 < ND; k0 += 32) {
    __syncthreads();
    *(uint4*)(&As[lrow * LDSPAD + lk]) = *(const uint4*)(&A[(size_t)(m0 + lrow) * ND + k0 + lk]);
    *(uint4*)(&Bs[lrow * LDSPAD + lk]) = *(const uint4*)(&Bt[(size_t)(n0 + lrow) * ND + k0 + lk]);
    __syncthreads();
    bf16x8 af = *(const bf16x8*)(&As[(wave * 16 + col) * LDSPAD + quad * 8]);
    for (int nt = 0; nt < 4; nt++) {
      bf16x8 bfr = *(const bf16x8*)(&Bs[(nt * 16 + col) * LDSPAD + quad * 8]);
      acc[nt] = __builtin_amdgcn_mfma_f32_16x16x32_bf16(af, bfr, acc[nt], 0, 0, 0);
    }
  }
  const int w = n0 >> 9;  // 0=Q 1=K 2=V (uniform per block)
  const float* bias = (w == 0) ? bq : (w == 1) ? bk : bv;
  for (int nt = 0; nt < 4; nt++) {
    const int ng = n0 + nt * 16 + col;
    const int nn = ng & 511, hh = nn >> 6, hd = nn & 63;
    const float bvv = bias[nn];
    for (int r = 0; r < 4; r++) {
      const int m = m0 + wave * 16 + quad * 4 + r;
      const int bb = m >> 11, s = m & (NS - 1);
      u16 v16 = f2bf(acc[nt][r] + bvv);
      if (w == 0) qb[((size_t)(bb * NH + hh) * NS + s) * NHD + hd] = v16;
      else if (w == 1) kb[((size_t)(bb * NH + hh) * NS + s) * NHD + hd] = v16;
      else {
        vtb[((size_t)(bb * NH + hh) * NHD + hd) * NS + s] = v16;
        vb[((size_t)(bb * NH + hh) * NS + s) * NHD + hd] = v16;
      }
    }
  }
}

// -------- output projection: bf16 MFMA, fp32 out --------
__global__ __launch_bounds__(256) void csa_gemm_out(const u16* __restrict__ A, const u16* __restrict__ Bt,
                                                    const float* __restrict__ bias, float* __restrict__ outp) {
  __shared__ __attribute__((aligned(16))) u16 As[64 * LDSPAD];
  __shared__ __attribute__((aligned(16))) u16 Bs[64 * LDSPAD];
  const int tid = threadIdx.x;
  const int wave = tid >> 6, lane = tid & 63;
  const int quad = lane >> 4, col = lane & 15;
  const int m0 = blockIdx.x * 64;
  const int n0 = blockIdx.y * 64;
  const f32x4 zf = {0.f, 0.f, 0.f, 0.f};
  f32x4 acc[4] = {zf, zf, zf, zf};
  const int lrow = tid >> 2, lk = (tid & 3) * 8;
  for (int k0 = 0; k0 < ND; k0 += 32) {
    __syncthreads();
    *(uint4*)(&As[lrow * LDSPAD + lk]) = *(const uint4*)(&A[(size_t)(m0 + lrow) * ND + k0 + lk]);
    *(uint4*)(&Bs[lrow * LDSPAD + lk]) = *(const uint4*)(&Bt[(size_t)(n0 + lrow) * ND + k0 + lk]);
    __syncthreads();
    bf16x8 af = *(const bf16x8*)(&As[(wave * 16 + col) * LDSPAD + quad * 8]);
    for (int nt = 0; nt < 4; nt++) {
      bf16x8 bfr = *(const bf16x8*)(&Bs[(nt * 16 + col) * LDSPAD + quad * 8]);
      acc[nt] = __builtin_amdgcn_mfma_f32_16x16x32_bf16(af, bfr, acc[nt], 0, 0, 0);
    }
  }
  for (int nt = 0; nt < 4; nt++) {
    const int n = n0 + nt * 16 + col;
    const float bvv = bias[n];
    for (int r = 0; r < 4; r++) {
      const int m = m0 + wave * 16 + quad * 4 + r;
      outp[(size_t)m * ND + n] = acc[nt][r] + bvv;
    }
  }
}

// -------- important-row attention: gathered rows, pure causal, 4-way strided key-split --------
// partials pbuf[((bh*4+chunk)*NILIST + row)*66] = {m, l, o[64] unnormalized}
__global__ __launch_bounds__(64) void csa_attn_imp(const u16* __restrict__ qb, const u16* __restrict__ kb,
                                                   const u16* __restrict__ vtb, const int* __restrict__ ilist,
                                                   float* __restrict__ pbuf) {
  const int lane = threadIdx.x;
  const int quad = lane >> 4, col = lane & 15;
  const int qt = blockIdx.x;     // 0..19
  const int chunk = blockIdx.y;  // 0..3
  const int bh = blockIdx.z;     // 0..15
  const int b = bh >> 3, h = bh & 7;

  const int* il = ilist + b * NILIST;
  const u16* qptr = qb + (size_t)(b * NH + h) * NS * NHD;
  const u16* kptr = kb + (size_t)(b * NH + h) * NS * NHD;
  const u16* vptr = vtb + (size_t)(b * NH + h) * NHD * NS;

  const int iq = il[qt * 16 + col];
  const int qrow = (iq < 0) ? 0 : iq;
  bf16x8 qf0 = *(const bf16x8*)(qptr + qrow * NHD + quad * 8);
  bf16x8 qf1 = *(const bf16x8*)(qptr + qrow * NHD + 32 + quad * 8);

  const f32x4 zf = {0.f, 0.f, 0.f, 0.f};
  float m_r[4], l_r[4];
  f32x4 of[4];
  int irow[4];
  for (int r = 0; r < 4; r++) {
    m_r[r] = -INFINITY;
    l_r[r] = 0.f;
    irow[r] = il[qt * 16 + quad * 4 + r];  // -1 for padding rows
  }
  for (int n = 0; n < 4; n++) of[n] = zf;

  __shared__ __attribute__((aligned(16))) u16 Pl[16 * LDSPAD];

  const int max_i = il[(qt * 16 + 15 > NKTOP - 1) ? (NKTOP - 1) : (qt * 16 + 15)];
  const int ntiles = (max_i >> 5) + 1;
  for (int t = chunk; t < ntiles; t += NCHUNK) {
    const int j0 = t * 32;
    f32x4 c0 = zf, c1 = zf;
    {
      bf16x8 k00 = *(const bf16x8*)(kptr + (j0 + col) * NHD + quad * 8);
      bf16x8 k01 = *(const bf16x8*)(kptr + (j0 + col) * NHD + 32 + quad * 8);
      c0 = __builtin_amdgcn_mfma_f32_16x16x32_bf16(qf0, k00, c0, 0, 0, 0);
      c0 = __builtin_amdgcn_mfma_f32_16x16x32_bf16(qf1, k01, c0, 0, 0, 0);
      bf16x8 k10 = *(const bf16x8*)(kptr + (j0 + 16 + col) * NHD + quad * 8);
      bf16x8 k11 = *(const bf16x8*)(kptr + (j0 + 16 + col) * NHD + 32 + quad * 8);
      c1 = __builtin_amdgcn_mfma_f32_16x16x32_bf16(qf0, k10, c1, 0, 0, 0);
      c1 = __builtin_amdgcn_mfma_f32_16x16x32_bf16(qf1, k11, c1, 0, 0, 0);
    }
    const int j_0 = j0 + col, j_1 = j0 + 16 + col;
    float p0s[4], p1s[4], alpha[4];
    for (int r = 0; r < 4; r++) {
      const int i = irow[r];
      float s0 = (j_0 <= i) ? c0[r] * 0.125f : -INFINITY;
      float s1 = (j_1 <= i) ? c1[r] * 0.125f : -INFINITY;
      float vmax = fmaxf(s0, s1);
      for (int off = 1; off < 16; off <<= 1) vmax = fmaxf(vmax, __shfl_xor(vmax, off, 64));
      float newm = fmaxf(m_r[r], vmax);
      bool dead = (newm == -INFINITY);
      float a = dead ? 1.f : __expf(m_r[r] - newm);
      float p0 = dead ? 0.f : __expf(s0 - newm);
      float p1 = dead ? 0.f : __expf(s1 - newm);
      float psum = p0 + p1;
      for (int off = 1; off < 16; off <<= 1) psum += __shfl_xor(psum, off, 64);
      m_r[r] = newm;
      l_r[r] = l_r[r] * a + psum;
      alpha[r] = a;
      p0s[r] = p0;
      p1s[r] = p1;
    }
    for (int n = 0; n < 4; n++)
      for (int r = 0; r < 4; r++) of[n][r] *= alpha[r];
    __syncthreads();
    for (int r = 0; r < 4; r++) {
      Pl[(quad * 4 + r) * LDSPAD + col] = f2bf(p0s[r]);
      Pl[(quad * 4 + r) * LDSPAD + 16 + col] = f2bf(p1s[r]);
    }
    __syncthreads();
    bf16x8 pf = *(const bf16x8*)(&Pl[col * LDSPAD + quad * 8]);
    for (int vn = 0; vn < 4; vn++) {
      bf16x8 vf = *(const bf16x8*)(vptr + (size_t)(vn * 16 + col) * NS + j0 + quad * 8);
      of[vn] = __builtin_amdgcn_mfma_f32_16x16x32_bf16(pf, vf, of[vn], 0, 0, 0);
    }
  }
  float* pr = pbuf + ((size_t)(bh * NCHUNK + chunk) * NILIST + qt * 16) * 66;
  for (int r = 0; r < 4; r++) {
    const int row = quad * 4 + r;
    if (col == 0) {
      pr[row * 66 + 0] = m_r[r];
      pr[row * 66 + 1] = l_r[r];
    }
    for (int vn = 0; vn < 4; vn++)
      pr[row * 66 + 2 + vn * 16 + col] = of[vn][r];
  }
}

// -------- merge important-row partials --------
__global__ __launch_bounds__(64) void csa_merge(const float* __restrict__ pbuf, const int* __restrict__ ilist,
                                                u16* __restrict__ attnb) {
  const int kp = blockIdx.x, h = blockIdx.y, b = blockIdx.z;
  const int lane = threadIdx.x;  // = d
  const int z = b * NH + h;
  float mc[NCHUNK], lc[NCHUNK], mstar = -INFINITY;
  for (int c = 0; c < NCHUNK; c++) {
    const float* base = pbuf + ((size_t)(z * NCHUNK + c) * NILIST + kp) * 66;
    mc[c] = base[0];
    lc[c] = base[1];
    mstar = fmaxf(mstar, mc[c]);
  }
  float lsum = 0.f, osum = 0.f;
  for (int c = 0; c < NCHUNK; c++) {
    const float* base = pbuf + ((size_t)(z * NCHUNK + c) * NILIST + kp) * 66;
    float w = (mc[c] == -INFINITY) ? 0.f : __expf(mc[c] - mstar);
    lsum += w * lc[c];
    osum += w * base[2 + lane];
  }
  const int i = ilist[b * NILIST + kp];
  attnb[((size_t)(b * NS + i) * NH + h) * NHD + lane] = f2bf(osum / lsum);
}

// -------- sparse-row attention: window + deduped random links, 1 wave per (row, head) --------
__global__ __launch_bounds__(256) void csa_attn_sparse(const u16* __restrict__ qb, const u16* __restrict__ kb,
                                                       const u16* __restrict__ vb, const int* __restrict__ rowimp,
                                                       const int* __restrict__ rand_idx, u16* __restrict__ attnb) {
  __shared__ __attribute__((aligned(16))) u16 ql[4][64];
  __shared__ float pl[4][64];
  __shared__ int jl[4][64];
  const int wave = threadIdx.x >> 6, lane = threadIdx.x & 63;
  const int i = blockIdx.x * 4 + wave;
  const int h = blockIdx.y, b = blockIdx.z;
  const int imp = rowimp[b * NS + i];

  const u16* qrow = qb + ((size_t)(b * NH + h) * NS + i) * NHD;
  const u16* kbase = kb + (size_t)(b * NH + h) * NS * NHD;
  const u16* vbase = vb + (size_t)(b * NH + h) * NS * NHD;

  // stage q into LDS (8 lanes x 16B)
  if (lane < 8) *(bf16x8*)(&ql[wave][lane * 8]) = *(const bf16x8*)(qrow + lane * 8);
  __syncthreads();

  // lane -> candidate key
  int j = 0, valid = 0;
  if (lane < 17) {
    j = i - NHWIN + lane;
    valid = (j >= 0);
  } else if (lane < 17 + NRC) {
    const int* rr = rand_idx + ((size_t)b * NS + i) * NRC;
    int c = lane - 17;
    j = rr[c];
    valid = (j <= i - NHWIN - 1);  // causal AND strictly below window
    for (int cp = 0; cp < c; cp++) valid &= (rr[cp] != j);  // first occurrence wins
  }
  const int jr = valid ? j : 0;

  // score = q . k[jr]
  float s = 0.f;
  const u16* krow = kbase + (size_t)jr * NHD;
  for (int c8 = 0; c8 < 8; c8++) {
    bf16x8 kv = *(const bf16x8*)(krow + c8 * 8);
    bf16x8 qv = *(const bf16x8*)(&ql[wave][c8 * 8]);
    for (int e = 0; e < 8; e++) s += bf2f(qv[e]) * bf2f(kv[e]);
  }
  s = valid ? s * 0.125f : -INFINITY;

  // softmax across wave
  float vmax = s;
  for (int off = 1; off < 64; off <<= 1) vmax = fmaxf(vmax, __shfl_xor(vmax, off, 64));
  float p = valid ? __expf(s - vmax) : 0.f;
  float lsum = p;
  for (int off = 1; off < 64; off <<= 1) lsum += __shfl_xor(lsum, off, 64);

  pl[wave][lane] = p;
  jl[wave][lane] = jr;
  __syncthreads();

  // PV: lane = output dim, coalesced V reads
  float o = 0.f;
  for (int jj = 0; jj < NKMAX; jj++) {
    float pj = pl[wave][jj];
    int jk = jl[wave][jj];
    o += pj * bf2f((short)vbase[(size_t)jk * NHD + lane]);
  }
  if (!imp)
    attnb[((size_t)(b * NS + i) * NH + h) * NHD + lane] = f2bf(o / lsum);
}

extern "C" void kernel_launch(void* const* d_in, const int* in_sizes, int n_in,
                              void* d_out, int out_size, void* d_ws, size_t ws_size,
                              hipStream_t stream) {
  const float* x = (const float*)d_in[0];
  const float* bq = (const float*)d_in[2];
  const float* bk = (const float*)d_in[4];
  const float* bv = (const float*)d_in[6];
  const float* bo = (const float*)d_in[8];
  const float* Ws1 = (const float*)d_in[9];
  const float* Ws2 = (const float*)d_in[11];
  const float* bs2 = (const float*)d_in[12];
  const int* rand_idx = (const int*)d_in[13];
  float* out = (float*)d_out;

  // workspace layout (~31.5 MB); hbuf/pbuf alias (scorer dead before attention)
  char* p = (char*)d_ws;
  u16* xb = (u16*)p;         p += (size_t)NB * NS * ND * 2;        // 4 MB
  u16* wt = (u16*)p;         p += (size_t)4 * ND * ND * 2;         // 2 MB  [Wq^T;Wk^T;Wv^T;Wo^T] bf16
  u16* qbuf = (u16*)p;       p += (size_t)NB * NH * NS * NHD * 2;  // 4 MB [B,H,S,HD]
  u16* kbuf = (u16*)p;       p += (size_t)NB * NH * NS * NHD * 2;  // 4 MB
  u16* vtbuf = (u16*)p;      p += (size_t)NB * NH * NHD * NS * 2;  // 4 MB [B,H,HD,S]
  u16* vbuf = (u16*)p;       p += (size_t)NB * NH * NS * NHD * 2;  // 4 MB [B,H,S,HD]
  u16* attnb = (u16*)p;      p += (size_t)NB * NS * ND * 2;        // 4 MB [B,S,H,HD]
  float* impbuf = (float*)p; p += (size_t)NB * NS * 4;
  int* rowimp = (int*)p;     p += (size_t)NB * NS * 4;
  int* ilist = (int*)p;      p += (size_t)NB * NILIST * 4;
  float* scratch = (float*)p;  // max(hbuf 4MB, pbuf 5.4MB)
  float* hbuf = scratch;
  float* pbuf = scratch;

  csa_cvt_x<<<dim3(NB * NS * ND / 1024), 256, 0, stream>>>(x, xb);
  csa_cvt_w<<<dim3(16, 16, 4), 256, 0, stream>>>((const float*)d_in[1], (const float*)d_in[3],
                                                 (const float*)d_in[5], (const float*)d_in[7], wt);

  // scorer chain (fp32 for exact ranking)
  csa_scorer_gemm<<<dim3(64, 4), 256, 0, stream>>>(x, Ws1, (const float*)d_in[10], hbuf);
  csa_logit<<<dim3(NB * NS), 256, 0, stream>>>(hbuf, Ws2, bs2, impbuf);
  csa_rank<<<dim3(NS / 256, NB), 256, 0, stream>>>(impbuf, rowimp);
  csa_ilist<<<dim3(NB), 256, 0, stream>>>(rowimp, ilist);

  // fused QKV projection
  csa_gemm_qkv<<<dim3(64, 24), 256, 0, stream>>>(xb, wt, bq, bk, bv, qbuf, kbuf, vtbuf, vbuf);

  // attention: important rows (MFMA, split-K) + sparse rows (per-wave)
  csa_attn_imp<<<dim3(NILIST / 16, NCHUNK, NB * NH), 64, 0, stream>>>(qbuf, kbuf, vtbuf, ilist, pbuf);
  csa_attn_sparse<<<dim3(NS / 4, NH, NB), 256, 0, stream>>>(qbuf, kbuf, vbuf, rowimp, rand_idx, attnb);
  csa_merge<<<dim3(NKTOP, NH, NB), 64, 0, stream>>>(pbuf, ilist, attnb);

  // output projection
  csa_gemm_out<<<dim3(64, 8), 256, 0, stream>>>(attnb, wt + 3 * (size_t)ND * ND, bo, out);
}

// Round 3
// 232.263 us; speedup vs baseline: 1.6487x; 1.2005x over previous
//
#include <hip/hip_runtime.h>
#include <math.h>

typedef unsigned short u16;
typedef unsigned int u32;
typedef unsigned long long u64;
typedef short bf16x8 __attribute__((ext_vector_type(8)));
typedef float f32x4 __attribute__((ext_vector_type(4)));

constexpr int NB = 2, NS = 2048, ND = 512, NH = 8, NHD = 64;
constexpr int NKTOP = 307, NHWIN = 16, NRC = 16;
constexpr int NILIST = 320;  // 20 tiles of 16 (padded with -1)
constexpr int NCHUNK = 4;    // key-split factor for important-row attention
constexpr int NKMAX = 33;    // 17 window + 16 random
constexpr int LDSPAD = 40;   // 80B row stride: breaks power-of-2 bank pattern, keeps 16B align

__device__ __forceinline__ u16 f2bf(float f) {
  u32 u = __builtin_bit_cast(u32, f);
  u32 r = (u + 0x7FFFu + ((u >> 16) & 1u)) >> 16;  // RNE
  return (u16)r;
}
__device__ __forceinline__ float bf2f(short v) {
  return __builtin_bit_cast(float, (u32)(u16)v << 16);
}

// ---------------- convert x (fp32 -> bf16) ----------------
__global__ __launch_bounds__(256) void csa_cvt_x(const float* __restrict__ x, u16* __restrict__ xb) {
  int i = (blockIdx.x * 256 + threadIdx.x) * 4;
  float4 v = *(const float4*)(x + i);
  u32 o0 = (u32)f2bf(v.x) | ((u32)f2bf(v.y) << 16);
  u32 o1 = (u32)f2bf(v.z) | ((u32)f2bf(v.w) << 16);
  *(uint2*)(xb + i) = make_uint2(o0, o1);
}

// -------- transpose + convert weights: W[K][N] fp32 -> Wt[N][K] bf16 (4 weights) --------
__global__ __launch_bounds__(256) void csa_cvt_w(const float* __restrict__ W0, const float* __restrict__ W1,
                                                 const float* __restrict__ W2, const float* __restrict__ W3,
                                                 u16* __restrict__ wt) {
  __shared__ float tile[32][33];
  int w = blockIdx.z;
  const float* src = (w == 0) ? W0 : (w == 1) ? W1 : (w == 2) ? W2 : W3;
  int kb = blockIdx.x * 32, nb = blockIdx.y * 32;
  int tx = threadIdx.x & 31, ty = threadIdx.x >> 5;
  for (int i = ty; i < 32; i += 8) tile[i][tx] = src[(size_t)(kb + i) * ND + nb + tx];
  __syncthreads();
  u16* dst = wt + (size_t)w * ND * ND;
  for (int i = ty; i < 32; i += 8) dst[(size_t)(nb + i) * ND + kb + tx] = f2bf(tile[tx][i]);
}

// -------- scorer SGEMM (fp32 for exact top-k ranking): H = relu(x @ Ws1 + bs1) --------
__global__ __launch_bounds__(256) void csa_scorer_gemm(const float* __restrict__ A, const float* __restrict__ Bw,
                                                       const float* __restrict__ bias, float* __restrict__ Hout) {
  __shared__ float As[16][64];
  __shared__ float Bs[16][64];
  const int tid = threadIdx.x;
  const int m0 = blockIdx.x * 64;
  const int n0 = blockIdx.y * 64;
  const int ty = tid >> 4, tx = tid & 15;
  float acc[4][4] = {};
  const int lrow = tid & 63, lkq = (tid >> 6) * 4;
  const int lkk = tid >> 4, lc4 = (tid & 15) * 4;
  for (int k0 = 0; k0 < ND; k0 += 16) {
    __syncthreads();
    float4 a = *(const float4*)(&A[(size_t)(m0 + lrow) * ND + k0 + lkq]);
    As[lkq + 0][lrow] = a.x; As[lkq + 1][lrow] = a.y; As[lkq + 2][lrow] = a.z; As[lkq + 3][lrow] = a.w;
    *(float4*)(&Bs[lkk][lc4]) = *(const float4*)(&Bw[(size_t)(k0 + lkk) * 256 + n0 + lc4]);
    __syncthreads();
    for (int k = 0; k < 16; k++) {
      float4 av = *(const float4*)(&As[k][ty * 4]);
      float4 bv = *(const float4*)(&Bs[k][tx * 4]);
      float aa[4] = {av.x, av.y, av.z, av.w};
      float bb[4] = {bv.x, bv.y, bv.z, bv.w};
      for (int i = 0; i < 4; i++)
        for (int j = 0; j < 4; j++)
          acc[i][j] += aa[i] * bb[j];
    }
  }
  for (int i = 0; i < 4; i++) {
    int m = m0 + ty * 4 + i;
    for (int j = 0; j < 4; j++) {
      int n = n0 + tx * 4 + j;
      Hout[(size_t)m * 256 + n] = fmaxf(acc[i][j] + bias[n], 0.f);
    }
  }
}

// -------- logit + sigmoid: one wave per row --------
__global__ __launch_bounds__(256) void csa_logit(const float* __restrict__ Hout, const float* __restrict__ Ws2,
                                                 const float* __restrict__ bs2, float* __restrict__ imp) {
  const int wave = threadIdx.x >> 6, lane = threadIdx.x & 63;
  const int row = blockIdx.x * 4 + wave;
  float4 h = *(const float4*)(&Hout[(size_t)row * 256 + lane * 4]);
  float4 w = *(const float4*)(&Ws2[lane * 4]);
  float s = h.x * w.x + h.y * w.y + h.z * w.z + h.w * w.w;
  for (int off = 1; off < 64; off <<= 1) s += __shfl_xor(s, off, 64);
  if (lane == 0) imp[row] = 1.f / (1.f + __expf(-(s + bs2[0])));
}

// -------- exact top-k (lax.top_k tie semantics: lower index wins), wave per 2 rows --------
__global__ __launch_bounds__(256) void csa_rank(const float* __restrict__ imp, int* __restrict__ rowimp) {
  __shared__ float vals[NS];
  const int b = blockIdx.y;
  {
    int t8 = threadIdx.x * 8;
    *(float4*)(&vals[t8]) = *(const float4*)(&imp[b * NS + t8]);
    *(float4*)(&vals[t8 + 4]) = *(const float4*)(&imp[b * NS + t8 + 4]);
  }
  __syncthreads();
  const int wave = threadIdx.x >> 6, lane = threadIdx.x & 63;
  const int s0 = blockIdx.x * 8 + wave * 2;  // two rows per wave
  const int s1 = s0 + 1;
  const float v0 = vals[s0], v1 = vals[s1];
  int r0 = 0, r1 = 0;
  for (int t = lane; t < NS; t += 64) {
    float u = vals[t];
    r0 += (int)((u > v0) | ((u == v0) & (t < s0)));
    r1 += (int)((u > v1) | ((u == v1) & (t < s1)));
  }
  for (int off = 1; off < 64; off <<= 1) {
    r0 += __shfl_xor(r0, off, 64);
    r1 += __shfl_xor(r1, off, 64);
  }
  if (lane == 0) {
    rowimp[b * NS + s0] = (r0 < NKTOP) ? 1 : 0;
    rowimp[b * NS + s1] = (r1 < NKTOP) ? 1 : 0;
  }
}

// -------- compact important rows into sorted list (exactly NKTOP per batch) --------
__global__ __launch_bounds__(256) void csa_ilist(const int* __restrict__ rowimp, int* __restrict__ ilist) {
  __shared__ int cs[256];
  int b = blockIdx.x, t = threadIdx.x;
  int flags[8], sum = 0;
  for (int k = 0; k < 8; k++) {
    flags[k] = rowimp[b * NS + t * 8 + k];
    sum += flags[k];
  }
  cs[t] = sum;
  __syncthreads();
  for (int off = 1; off < 256; off <<= 1) {
    int v = (t >= off) ? cs[t - off] : 0;
    __syncthreads();
    cs[t] += v;
    __syncthreads();
  }
  int pos = cs[t] - sum;  // exclusive prefix
  for (int k = 0; k < 8; k++)
    if (flags[k]) ilist[b * NILIST + pos++] = t * 8 + k;
  if (t < NILIST - NKTOP) ilist[b * NILIST + NKTOP + t] = -1;
}

// -------- fused QKV projection: bf16 MFMA, N=1536 over [Wq^T;Wk^T;Wv^T] --------
__global__ __launch_bounds__(256) void csa_gemm_qkv(const u16* __restrict__ A, const u16* __restrict__ Bt,
                                                    const float* __restrict__ bq, const float* __restrict__ bk,
                                                    const float* __restrict__ bv, u16* __restrict__ qb,
                                                    u16* __restrict__ kb, u16* __restrict__ vtb,
                                                    u16* __restrict__ vb) {
  __shared__ __attribute__((aligned(16))) u16 As[64 * LDSPAD];
  __shared__ __attribute__((aligned(16))) u16 Bs[64 * LDSPAD];
  const int tid = threadIdx.x;
  const int wave = tid >> 6, lane = tid & 63;
  const int quad = lane >> 4, col = lane & 15;
  const int m0 = blockIdx.x * 64;
  const int n0 = blockIdx.y * 64;
  const f32x4 zf = {0.f, 0.f, 0.f, 0.f};
  f32x4 acc[4] = {zf, zf, zf, zf};
  const int lrow = tid >> 2, lk = (tid & 3) * 8;
  for (int k0 = 0; k0 < ND; k0 += 32) {
    __syncthreads();
    *(uint4*)(&As[lrow * LDSPAD + lk]) = *(const uint4*)(&A[(size_t)(m0 + lrow) * ND + k0 + lk]);
    *(uint4*)(&Bs[lrow * LDSPAD + lk]) = *(const uint4*)(&Bt[(size_t)(n0 + lrow) * ND + k0 + lk]);
    __syncthreads();
    bf16x8 af = *(const bf16x8*)(&As[(wave * 16 + col) * LDSPAD + quad * 8]);
    for (int nt = 0; nt < 4; nt++) {
      bf16x8 bfr = *(const bf16x8*)(&Bs[(nt * 16 + col) * LDSPAD + quad * 8]);
      acc[nt] = __builtin_amdgcn_mfma_f32_16x16x32_bf16(af, bfr, acc[nt], 0, 0, 0);
    }
  }
  const int w = n0 >> 9;  // 0=Q 1=K 2=V (uniform per block)
  const float* bias = (w == 0) ? bq : (w == 1) ? bk : bv;
  for (int nt = 0; nt < 4; nt++) {
    const int ng = n0 + nt * 16 + col;
    const int nn = ng & 511, hh = nn >> 6, hd = nn & 63;
    const float bvv = bias[nn];
    for (int r = 0; r < 4; r++) {
      const int m = m0 + wave * 16 + quad * 4 + r;
      const int bb = m >> 11, s = m & (NS - 1);
      u16 v16 = f2bf(acc[nt][r] + bvv);
      if (w == 0) qb[((size_t)(bb * NH + hh) * NS + s) * NHD + hd] = v16;
      else if (w == 1) kb[((size_t)(bb * NH + hh) * NS + s) * NHD + hd] = v16;
      else {
        vtb[((size_t)(bb * NH + hh) * NHD + hd) * NS + s] = v16;
        vb[((size_t)(bb * NH + hh) * NS + s) * NHD + hd] = v16;
      }
    }
  }
}

// -------- output projection: bf16 MFMA, fp32 out --------
__global__ __launch_bounds__(256) void csa_gemm_out(const u16* __restrict__ A, const u16* __restrict__ Bt,
                                                    const float* __restrict__ bias, float* __restrict__ outp) {
  __shared__ __attribute__((aligned(16))) u16 As[64 * LDSPAD];
  __shared__ __attribute__((aligned(16))) u16 Bs[64 * LDSPAD];
  const int tid = threadIdx.x;
  const int wave = tid >> 6, lane = tid & 63;
  const int quad = lane >> 4, col = lane & 15;
  const int m0 = blockIdx.x * 64;
  const int n0 = blockIdx.y * 64;
  const f32x4 zf = {0.f, 0.f, 0.f, 0.f};
  f32x4 acc[4] = {zf, zf, zf, zf};
  const int lrow = tid >> 2, lk = (tid & 3) * 8;
  for (int k0 = 0; k0 < ND; k0 += 32) {
    __syncthreads();
    *(uint4*)(&As[lrow * LDSPAD + lk]) = *(const uint4*)(&A[(size_t)(m0 + lrow) * ND + k0 + lk]);
    *(uint4*)(&Bs[lrow * LDSPAD + lk]) = *(const uint4*)(&Bt[(size_t)(n0 + lrow) * ND + k0 + lk]);
    __syncthreads();
    bf16x8 af = *(const bf16x8*)(&As[(wave * 16 + col) * LDSPAD + quad * 8]);
    for (int nt = 0; nt < 4; nt++) {
      bf16x8 bfr = *(const bf16x8*)(&Bs[(nt * 16 + col) * LDSPAD + quad * 8]);
      acc[nt] = __builtin_amdgcn_mfma_f32_16x16x32_bf16(af, bfr, acc[nt], 0, 0, 0);
    }
  }
  for (int nt = 0; nt < 4; nt++) {
    const int n = n0 + nt * 16 + col;
    const float bvv = bias[n];
    for (int r = 0; r < 4; r++) {
      const int m = m0 + wave * 16 + quad * 4 + r;
      outp[(size_t)m * ND + n] = acc[nt][r] + bvv;
    }
  }
}

// -------- important-row attention: gathered rows, pure causal, 4-way strided key-split --------
// partials pbuf[((bh*4+chunk)*NILIST + row)*66] = {m, l, o[64] unnormalized}
__global__ __launch_bounds__(64) void csa_attn_imp(const u16* __restrict__ qb, const u16* __restrict__ kb,
                                                   const u16* __restrict__ vtb, const int* __restrict__ ilist,
                                                   float* __restrict__ pbuf) {
  const int lane = threadIdx.x;
  const int quad = lane >> 4, col = lane & 15;
  const int qt = blockIdx.x;     // 0..19
  const int chunk = blockIdx.y;  // 0..3
  const int bh = blockIdx.z;     // 0..15
  const int b = bh >> 3, h = bh & 7;

  const int* il = ilist + b * NILIST;
  const u16* qptr = qb + (size_t)(b * NH + h) * NS * NHD;
  const u16* kptr = kb + (size_t)(b * NH + h) * NS * NHD;
  const u16* vptr = vtb + (size_t)(b * NH + h) * NHD * NS;

  const int iq = il[qt * 16 + col];
  const int qrow = (iq < 0) ? 0 : iq;
  bf16x8 qf0 = *(const bf16x8*)(qptr + qrow * NHD + quad * 8);
  bf16x8 qf1 = *(const bf16x8*)(qptr + qrow * NHD + 32 + quad * 8);

  const f32x4 zf = {0.f, 0.f, 0.f, 0.f};
  float m_r[4], l_r[4];
  f32x4 of[4];
  int irow[4];
  for (int r = 0; r < 4; r++) {
    m_r[r] = -INFINITY;
    l_r[r] = 0.f;
    irow[r] = il[qt * 16 + quad * 4 + r];  // -1 for padding rows
  }
  for (int n = 0; n < 4; n++) of[n] = zf;

  __shared__ __attribute__((aligned(16))) u16 Pl[16 * LDSPAD];

  const int max_i = il[(qt * 16 + 15 > NKTOP - 1) ? (NKTOP - 1) : (qt * 16 + 15)];
  const int ntiles = (max_i >> 5) + 1;
  for (int t = chunk; t < ntiles; t += NCHUNK) {
    const int j0 = t * 32;
    f32x4 c0 = zf, c1 = zf;
    {
      bf16x8 k00 = *(const bf16x8*)(kptr + (j0 + col) * NHD + quad * 8);
      bf16x8 k01 = *(const bf16x8*)(kptr + (j0 + col) * NHD + 32 + quad * 8);
      c0 = __builtin_amdgcn_mfma_f32_16x16x32_bf16(qf0, k00, c0, 0, 0, 0);
      c0 = __builtin_amdgcn_mfma_f32_16x16x32_bf16(qf1, k01, c0, 0, 0, 0);
      bf16x8 k10 = *(const bf16x8*)(kptr + (j0 + 16 + col) * NHD + quad * 8);
      bf16x8 k11 = *(const bf16x8*)(kptr + (j0 + 16 + col) * NHD + 32 + quad * 8);
      c1 = __builtin_amdgcn_mfma_f32_16x16x32_bf16(qf0, k10, c1, 0, 0, 0);
      c1 = __builtin_amdgcn_mfma_f32_16x16x32_bf16(qf1, k11, c1, 0, 0, 0);
    }
    const int j_0 = j0 + col, j_1 = j0 + 16 + col;
    float p0s[4], p1s[4], alpha[4];
    for (int r = 0; r < 4; r++) {
      const int i = irow[r];
      float s0 = (j_0 <= i) ? c0[r] * 0.125f : -INFINITY;
      float s1 = (j_1 <= i) ? c1[r] * 0.125f : -INFINITY;
      float vmax = fmaxf(s0, s1);
      for (int off = 1; off < 16; off <<= 1) vmax = fmaxf(vmax, __shfl_xor(vmax, off, 64));
      float newm = fmaxf(m_r[r], vmax);
      bool dead = (newm == -INFINITY);
      float a = dead ? 1.f : __expf(m_r[r] - newm);
      float p0 = dead ? 0.f : __expf(s0 - newm);
      float p1 = dead ? 0.f : __expf(s1 - newm);
      float psum = p0 + p1;
      for (int off = 1; off < 16; off <<= 1) psum += __shfl_xor(psum, off, 64);
      m_r[r] = newm;
      l_r[r] = l_r[r] * a + psum;
      alpha[r] = a;
      p0s[r] = p0;
      p1s[r] = p1;
    }
    for (int n = 0; n < 4; n++)
      for (int r = 0; r < 4; r++) of[n][r] *= alpha[r];
    __syncthreads();
    for (int r = 0; r < 4; r++) {
      Pl[(quad * 4 + r) * LDSPAD + col] = f2bf(p0s[r]);
      Pl[(quad * 4 + r) * LDSPAD + 16 + col] = f2bf(p1s[r]);
    }
    __syncthreads();
    bf16x8 pf = *(const bf16x8*)(&Pl[col * LDSPAD + quad * 8]);
    for (int vn = 0; vn < 4; vn++) {
      bf16x8 vf = *(const bf16x8*)(vptr + (size_t)(vn * 16 + col) * NS + j0 + quad * 8);
      of[vn] = __builtin_amdgcn_mfma_f32_16x16x32_bf16(pf, vf, of[vn], 0, 0, 0);
    }
  }
  float* pr = pbuf + ((size_t)(bh * NCHUNK + chunk) * NILIST + qt * 16) * 66;
  for (int r = 0; r < 4; r++) {
    const int row = quad * 4 + r;
    if (col == 0) {
      pr[row * 66 + 0] = m_r[r];
      pr[row * 66 + 1] = l_r[r];
    }
    for (int vn = 0; vn < 4; vn++)
      pr[row * 66 + 2 + vn * 16 + col] = of[vn][r];
  }
}

// -------- merge important-row partials --------
__global__ __launch_bounds__(64) void csa_merge(const float* __restrict__ pbuf, const int* __restrict__ ilist,
                                                u16* __restrict__ attnb) {
  const int kp = blockIdx.x, h = blockIdx.y, b = blockIdx.z;
  const int lane = threadIdx.x;  // = d
  const int z = b * NH + h;
  float mc[NCHUNK], lc[NCHUNK], mstar = -INFINITY;
  for (int c = 0; c < NCHUNK; c++) {
    const float* base = pbuf + ((size_t)(z * NCHUNK + c) * NILIST + kp) * 66;
    mc[c] = base[0];
    lc[c] = base[1];
    mstar = fmaxf(mstar, mc[c]);
  }
  float lsum = 0.f, osum = 0.f;
  for (int c = 0; c < NCHUNK; c++) {
    const float* base = pbuf + ((size_t)(z * NCHUNK + c) * NILIST + kp) * 66;
    float w = (mc[c] == -INFINITY) ? 0.f : __expf(mc[c] - mstar);
    lsum += w * lc[c];
    osum += w * base[2 + lane];
  }
  const int i = ilist[b * NILIST + kp];
  attnb[((size_t)(b * NS + i) * NH + h) * NHD + lane] = f2bf(osum / lsum);
}

// -------- sparse-row attention: window + deduped random links, 1 wave per (row, head) --------
__global__ __launch_bounds__(256) void csa_attn_sparse(const u16* __restrict__ qb, const u16* __restrict__ kb,
                                                       const u16* __restrict__ vb, const int* __restrict__ rowimp,
                                                       const int* __restrict__ rand_idx, u16* __restrict__ attnb) {
  __shared__ __attribute__((aligned(16))) u16 ql[4][64];
  __shared__ float pl[4][64];
  __shared__ int jl[4][64];
  const int wave = threadIdx.x >> 6, lane = threadIdx.x & 63;
  const int i = blockIdx.x * 4 + wave;
  const int h = blockIdx.y, b = blockIdx.z;
  const int imp = rowimp[b * NS + i];

  const u16* qrow = qb + ((size_t)(b * NH + h) * NS + i) * NHD;
  const u16* kbase = kb + (size_t)(b * NH + h) * NS * NHD;
  const u16* vbase = vb + (size_t)(b * NH + h) * NS * NHD;

  // stage q into LDS (8 lanes x 16B)
  if (lane < 8) *(bf16x8*)(&ql[wave][lane * 8]) = *(const bf16x8*)(qrow + lane * 8);
  __syncthreads();

  // lane -> candidate key
  int j = 0, valid = 0;
  if (lane < 17) {
    j = i - NHWIN + lane;
    valid = (j >= 0);
  } else if (lane < 17 + NRC) {
    const int* rr = rand_idx + ((size_t)b * NS + i) * NRC;
    int c = lane - 17;
    j = rr[c];
    valid = (j <= i - NHWIN - 1);  // causal AND strictly below window
    for (int cp = 0; cp < c; cp++) valid &= (rr[cp] != j);  // first occurrence wins
  }
  const int jr = valid ? j : 0;

  // score = q . k[jr]
  float s = 0.f;
  const u16* krow = kbase + (size_t)jr * NHD;
  for (int c8 = 0; c8 < 8; c8++) {
    bf16x8 kv = *(const bf16x8*)(krow + c8 * 8);
    bf16x8 qv = *(const bf16x8*)(&ql[wave][c8 * 8]);
    for (int e = 0; e < 8; e++) s += bf2f(qv[e]) * bf2f(kv[e]);
  }
  s = valid ? s * 0.125f : -INFINITY;

  // softmax across wave
  float vmax = s;
  for (int off = 1; off < 64; off <<= 1) vmax = fmaxf(vmax, __shfl_xor(vmax, off, 64));
  float p = valid ? __expf(s - vmax) : 0.f;
  float lsum = p;
  for (int off = 1; off < 64; off <<= 1) lsum += __shfl_xor(lsum, off, 64);

  pl[wave][lane] = p;
  jl[wave][lane] = jr;
  __syncthreads();

  // PV: lane = output dim, coalesced V reads
  float o = 0.f;
  for (int jj = 0; jj < NKMAX; jj++) {
    float pj = pl[wave][jj];
    int jk = jl[wave][jj];
    o += pj * bf2f((short)vbase[(size_t)jk * NHD + lane]);
  }
  if (!imp)
    attnb[((size_t)(b * NS + i) * NH + h) * NHD + lane] = f2bf(o / lsum);
}

extern "C" void kernel_launch(void* const* d_in, const int* in_sizes, int n_in,
                              void* d_out, int out_size, void* d_ws, size_t ws_size,
                              hipStream_t stream) {
  const float* x = (const float*)d_in[0];
  const float* bq = (const float*)d_in[2];
  const float* bk = (const float*)d_in[4];
  const float* bv = (const float*)d_in[6];
  const float* bo = (const float*)d_in[8];
  const float* Ws1 = (const float*)d_in[9];
  const float* Ws2 = (const float*)d_in[11];
  const float* bs2 = (const float*)d_in[12];
  const int* rand_idx = (const int*)d_in[13];
  float* out = (float*)d_out;

  // workspace layout (~31.5 MB); hbuf/pbuf alias (scorer dead before attention)
  char* p = (char*)d_ws;
  u16* xb = (u16*)p;         p += (size_t)NB * NS * ND * 2;        // 4 MB
  u16* wt = (u16*)p;         p += (size_t)4 * ND * ND * 2;         // 2 MB  [Wq^T;Wk^T;Wv^T;Wo^T] bf16
  u16* qbuf = (u16*)p;       p += (size_t)NB * NH * NS * NHD * 2;  // 4 MB [B,H,S,HD]
  u16* kbuf = (u16*)p;       p += (size_t)NB * NH * NS * NHD * 2;  // 4 MB
  u16* vtbuf = (u16*)p;      p += (size_t)NB * NH * NHD * NS * 2;  // 4 MB [B,H,HD,S]
  u16* vbuf = (u16*)p;       p += (size_t)NB * NH * NS * NHD * 2;  // 4 MB [B,H,S,HD]
  u16* attnb = (u16*)p;      p += (size_t)NB * NS * ND * 2;        // 4 MB [B,S,H,HD]
  float* impbuf = (float*)p; p += (size_t)NB * NS * 4;
  int* rowimp = (int*)p;     p += (size_t)NB * NS * 4;
  int* ilist = (int*)p;      p += (size_t)NB * NILIST * 4;
  float* scratch = (float*)p;  // max(hbuf 4MB, pbuf 5.4MB)
  float* hbuf = scratch;
  float* pbuf = scratch;

  csa_cvt_x<<<dim3(NB * NS * ND / 1024), 256, 0, stream>>>(x, xb);
  csa_cvt_w<<<dim3(16, 16, 4), 256, 0, stream>>>((const float*)d_in[1], (const float*)d_in[3],
                                                 (const float*)d_in[5], (const float*)d_in[7], wt);

  // scorer chain (fp32 for exact ranking)
  csa_scorer_gemm<<<dim3(64, 4), 256, 0, stream>>>(x, Ws1, (const float*)d_in[10], hbuf);
  csa_logit<<<dim3(NB * NS / 4), 256, 0, stream>>>(hbuf, Ws2, bs2, impbuf);
  csa_rank<<<dim3(NS / 8, NB), 256, 0, stream>>>(impbuf, rowimp);
  csa_ilist<<<dim3(NB), 256, 0, stream>>>(rowimp, ilist);

  // fused QKV projection
  csa_gemm_qkv<<<dim3(64, 24), 256, 0, stream>>>(xb, wt, bq, bk, bv, qbuf, kbuf, vtbuf, vbuf);

  // attention: important rows (MFMA, split-K) + sparse rows (per-wave)
  csa_attn_imp<<<dim3(NILIST / 16, NCHUNK, NB * NH), 64, 0, stream>>>(qbuf, kbuf, vtbuf, ilist, pbuf);
  csa_attn_sparse<<<dim3(NS / 4, NH, NB), 256, 0, stream>>>(qbuf, kbuf, vbuf, rowimp, rand_idx, attnb);
  csa_merge<<<dim3(NKTOP, NH, NB), 64, 0, stream>>>(pbuf, ilist, attnb);

  // output projection
  csa_gemm_out<<<dim3(64, 8), 256, 0, stream>>>(attnb, wt + 3 * (size_t)ND * ND, bo, out);
}

// Round 4
// 220.380 us; speedup vs baseline: 1.7376x; 1.0539x over previous
//
#include <hip/hip_runtime.h>
#include <math.h>

typedef unsigned short u16;
typedef unsigned int u32;
typedef unsigned long long u64;
typedef short bf16x8 __attribute__((ext_vector_type(8)));
typedef float f32x4 __attribute__((ext_vector_type(4)));

constexpr int NB = 2, NS = 2048, ND = 512, NH = 8, NHD = 64;
constexpr int NKTOP = 307, NHWIN = 16, NRC = 16;
constexpr int NILIST = 320;  // 20 tiles of 16 (padded with -1)
constexpr int NCHUNK = 4;    // key-split factor for important-row attention
constexpr int NKMAX = 33;    // 17 window + 16 random
constexpr int LDSPAD = 40;   // 80B row stride: breaks power-of-2 bank pattern, keeps 16B align

__device__ __forceinline__ u16 f2bf(float f) {
  u32 u = __builtin_bit_cast(u32, f);
  u32 r = (u + 0x7FFFu + ((u >> 16) & 1u)) >> 16;  // RNE
  return (u16)r;
}
__device__ __forceinline__ float bf2f(short v) {
  return __builtin_bit_cast(float, (u32)(u16)v << 16);
}

// -------- transpose + convert weights: W[K][N] fp32 -> Wt[N][K] bf16 (4 weights) --------
__global__ __launch_bounds__(256) void csa_cvt_w(const float* __restrict__ W0, const float* __restrict__ W1,
                                                 const float* __restrict__ W2, const float* __restrict__ W3,
                                                 u16* __restrict__ wt) {
  __shared__ float tile[32][33];
  int w = blockIdx.z;
  const float* src = (w == 0) ? W0 : (w == 1) ? W1 : (w == 2) ? W2 : W3;
  int kb = blockIdx.x * 32, nb = blockIdx.y * 32;
  int tx = threadIdx.x & 31, ty = threadIdx.x >> 5;
  for (int i = ty; i < 32; i += 8) tile[i][tx] = src[(size_t)(kb + i) * ND + nb + tx];
  __syncthreads();
  u16* dst = wt + (size_t)w * ND * ND;
  for (int i = ty; i < 32; i += 8) dst[(size_t)(nb + i) * ND + kb + tx] = f2bf(tile[tx][i]);
}

// -------- fused scorer: logit[row] += relu(x@Ws1+bs1) . Ws2  (fp32, partial-N atomics) --------
// sigmoid and bs2 are strictly monotone / constant -> ranking on raw logits is identical.
__global__ __launch_bounds__(256) void csa_scorer(const float* __restrict__ x, const float* __restrict__ Ws1,
                                                  const float* __restrict__ bs1, const float* __restrict__ Ws2,
                                                  float* __restrict__ logit) {
  __shared__ float As[32][33];  // [k][m]
  __shared__ float Bs[32][68];  // [k][n]
  const int tid = threadIdx.x;
  const int m0 = blockIdx.x * 32, n0 = blockIdx.y * 64;
  const int r2 = (tid >> 4) * 2;  // rows r2, r2+1
  const int c4 = (tid & 15) * 4;  // cols c4..c4+3
  float acc[2][4] = {};
  const int arow = tid & 31, aks = (tid >> 5) * 4;
  const int bk = tid >> 3, bc = (tid & 7) * 8;
  for (int k0 = 0; k0 < ND; k0 += 32) {
    __syncthreads();
    float4 av = *(const float4*)(&x[(size_t)(m0 + arow) * ND + k0 + aks]);
    As[aks + 0][arow] = av.x;
    As[aks + 1][arow] = av.y;
    As[aks + 2][arow] = av.z;
    As[aks + 3][arow] = av.w;
    *(float4*)(&Bs[bk][bc]) = *(const float4*)(&Ws1[(size_t)(k0 + bk) * 256 + n0 + bc]);
    *(float4*)(&Bs[bk][bc + 4]) = *(const float4*)(&Ws1[(size_t)(k0 + bk) * 256 + n0 + bc + 4]);
    __syncthreads();
    for (int k = 0; k < 32; k++) {
      float a0 = As[k][r2], a1 = As[k][r2 + 1];
      float4 b = *(const float4*)(&Bs[k][c4]);
      acc[0][0] += a0 * b.x; acc[0][1] += a0 * b.y; acc[0][2] += a0 * b.z; acc[0][3] += a0 * b.w;
      acc[1][0] += a1 * b.x; acc[1][1] += a1 * b.y; acc[1][2] += a1 * b.z; acc[1][3] += a1 * b.w;
    }
  }
  float4 w2 = *(const float4*)(&Ws2[n0 + c4]);
  float4 b1 = *(const float4*)(&bs1[n0 + c4]);
  float p0 = fmaxf(acc[0][0] + b1.x, 0.f) * w2.x + fmaxf(acc[0][1] + b1.y, 0.f) * w2.y +
             fmaxf(acc[0][2] + b1.z, 0.f) * w2.z + fmaxf(acc[0][3] + b1.w, 0.f) * w2.w;
  float p1 = fmaxf(acc[1][0] + b1.x, 0.f) * w2.x + fmaxf(acc[1][1] + b1.y, 0.f) * w2.y +
             fmaxf(acc[1][2] + b1.z, 0.f) * w2.z + fmaxf(acc[1][3] + b1.w, 0.f) * w2.w;
  for (int off = 1; off < 16; off <<= 1) {
    p0 += __shfl_xor(p0, off, 64);
    p1 += __shfl_xor(p1, off, 64);
  }
  if ((tid & 15) == 0) {
    atomicAdd(&logit[m0 + r2], p0);
    atomicAdd(&logit[m0 + r2 + 1], p1);
  }
}

// -------- exact top-k on logits (lax.top_k tie semantics: lower index wins), wave per 2 rows --------
__global__ __launch_bounds__(256) void csa_rank(const float* __restrict__ imp, int* __restrict__ rowimp) {
  __shared__ float vals[NS];
  const int b = blockIdx.y;
  {
    int t8 = threadIdx.x * 8;
    *(float4*)(&vals[t8]) = *(const float4*)(&imp[b * NS + t8]);
    *(float4*)(&vals[t8 + 4]) = *(const float4*)(&imp[b * NS + t8 + 4]);
  }
  __syncthreads();
  const int wave = threadIdx.x >> 6, lane = threadIdx.x & 63;
  const int s0 = blockIdx.x * 8 + wave * 2;  // two rows per wave
  const int s1 = s0 + 1;
  const float v0 = vals[s0], v1 = vals[s1];
  int r0 = 0, r1 = 0;
  for (int t = lane; t < NS; t += 64) {
    float u = vals[t];
    r0 += (int)((u > v0) | ((u == v0) & (t < s0)));
    r1 += (int)((u > v1) | ((u == v1) & (t < s1)));
  }
  for (int off = 1; off < 64; off <<= 1) {
    r0 += __shfl_xor(r0, off, 64);
    r1 += __shfl_xor(r1, off, 64);
  }
  if (lane == 0) {
    rowimp[b * NS + s0] = (r0 < NKTOP) ? 1 : 0;
    rowimp[b * NS + s1] = (r1 < NKTOP) ? 1 : 0;
  }
}

// -------- compact important rows into sorted list (exactly NKTOP per batch) --------
__global__ __launch_bounds__(256) void csa_ilist(const int* __restrict__ rowimp, int* __restrict__ ilist) {
  __shared__ int cs[256];
  int b = blockIdx.x, t = threadIdx.x;
  int flags[8], sum = 0;
  for (int k = 0; k < 8; k++) {
    flags[k] = rowimp[b * NS + t * 8 + k];
    sum += flags[k];
  }
  cs[t] = sum;
  __syncthreads();
  for (int off = 1; off < 256; off <<= 1) {
    int v = (t >= off) ? cs[t - off] : 0;
    __syncthreads();
    cs[t] += v;
    __syncthreads();
  }
  int pos = cs[t] - sum;  // exclusive prefix
  for (int k = 0; k < 8; k++)
    if (flags[k]) ilist[b * NILIST + pos++] = t * 8 + k;
  if (t < NILIST - NKTOP) ilist[b * NILIST + NKTOP + t] = -1;
}

// -------- fused QKV projection: fp32 x staged->bf16, MFMA 128x64 tile, N=1536 --------
__global__ __launch_bounds__(256) void csa_gemm_qkv(const float* __restrict__ x, const u16* __restrict__ Bt,
                                                    const float* __restrict__ bq, const float* __restrict__ bk,
                                                    const float* __restrict__ bv, u16* __restrict__ qb,
                                                    u16* __restrict__ kb, u16* __restrict__ vtb,
                                                    u16* __restrict__ vb) {
  __shared__ __attribute__((aligned(16))) u16 As[128 * LDSPAD];
  __shared__ __attribute__((aligned(16))) u16 Bs[64 * LDSPAD];
  const int tid = threadIdx.x;
  const int wave = tid >> 6, lane = tid & 63;
  const int quad = lane >> 4, col = lane & 15;
  const int m0 = blockIdx.x * 128;
  const int n0 = blockIdx.y * 64;
  const f32x4 zf = {0.f, 0.f, 0.f, 0.f};
  f32x4 acc[2][4] = {{zf, zf, zf, zf}, {zf, zf, zf, zf}};
  const int sar = tid >> 1, sak = (tid & 1) * 16;  // A: 128 rows x 32 k
  const int sbr = tid >> 2, sbk = (tid & 3) * 8;   // B: 64 rows x 32 k
  for (int k0 = 0; k0 < ND; k0 += 32) {
    __syncthreads();
    {
      const float* xp = &x[(size_t)(m0 + sar) * ND + k0 + sak];
      float4 v0 = *(const float4*)(xp), v1 = *(const float4*)(xp + 4);
      float4 v2 = *(const float4*)(xp + 8), v3 = *(const float4*)(xp + 12);
      u32 w0 = (u32)f2bf(v0.x) | ((u32)f2bf(v0.y) << 16);
      u32 w1 = (u32)f2bf(v0.z) | ((u32)f2bf(v0.w) << 16);
      u32 w2 = (u32)f2bf(v1.x) | ((u32)f2bf(v1.y) << 16);
      u32 w3 = (u32)f2bf(v1.z) | ((u32)f2bf(v1.w) << 16);
      u32 w4 = (u32)f2bf(v2.x) | ((u32)f2bf(v2.y) << 16);
      u32 w5 = (u32)f2bf(v2.z) | ((u32)f2bf(v2.w) << 16);
      u32 w6 = (u32)f2bf(v3.x) | ((u32)f2bf(v3.y) << 16);
      u32 w7 = (u32)f2bf(v3.z) | ((u32)f2bf(v3.w) << 16);
      u32* ap = (u32*)&As[sar * LDSPAD + sak];
      ap[0] = w0; ap[1] = w1; ap[2] = w2; ap[3] = w3;
      ap[4] = w4; ap[5] = w5; ap[6] = w6; ap[7] = w7;
    }
    *(uint4*)(&Bs[sbr * LDSPAD + sbk]) = *(const uint4*)(&Bt[(size_t)(n0 + sbr) * ND + k0 + sbk]);
    __syncthreads();
    bf16x8 af0 = *(const bf16x8*)(&As[(wave * 32 + col) * LDSPAD + quad * 8]);
    bf16x8 af1 = *(const bf16x8*)(&As[(wave * 32 + 16 + col) * LDSPAD + quad * 8]);
    for (int c = 0; c < 4; c++) {
      bf16x8 bfr = *(const bf16x8*)(&Bs[(c * 16 + col) * LDSPAD + quad * 8]);
      acc[0][c] = __builtin_amdgcn_mfma_f32_16x16x32_bf16(af0, bfr, acc[0][c], 0, 0, 0);
      acc[1][c] = __builtin_amdgcn_mfma_f32_16x16x32_bf16(af1, bfr, acc[1][c], 0, 0, 0);
    }
  }
  const int w = n0 >> 9;  // 0=Q 1=K 2=V (uniform per block; 64-tiles align in 512 regions)
  const float* bias = (w == 0) ? bq : (w == 1) ? bk : bv;
  for (int c = 0; c < 4; c++) {
    const int ng = n0 + c * 16 + col;
    const int nn = ng & 511, hh = nn >> 6, hd = nn & 63;
    const float bvv = bias[nn];
    for (int r = 0; r < 2; r++) {
      for (int rr = 0; rr < 4; rr++) {
        const int m = m0 + wave * 32 + r * 16 + quad * 4 + rr;
        const int bb = m >> 11, s = m & (NS - 1);
        u16 v16 = f2bf(acc[r][c][rr] + bvv);
        if (w == 0) qb[((size_t)(bb * NH + hh) * NS + s) * NHD + hd] = v16;
        else if (w == 1) kb[((size_t)(bb * NH + hh) * NS + s) * NHD + hd] = v16;
        else {
          vtb[((size_t)(bb * NH + hh) * NHD + hd) * NS + s] = v16;
          vb[((size_t)(bb * NH + hh) * NS + s) * NHD + hd] = v16;
        }
      }
    }
  }
}

// -------- output projection: bf16 MFMA 64x64, fp32 out --------
__global__ __launch_bounds__(256) void csa_gemm_out(const u16* __restrict__ A, const u16* __restrict__ Bt,
                                                    const float* __restrict__ bias, float* __restrict__ outp) {
  __shared__ __attribute__((aligned(16))) u16 As[64 * LDSPAD];
  __shared__ __attribute__((aligned(16))) u16 Bs[64 * LDSPAD];
  const int tid = threadIdx.x;
  const int wave = tid >> 6, lane = tid & 63;
  const int quad = lane >> 4, col = lane & 15;
  const int m0 = blockIdx.x * 64;
  const int n0 = blockIdx.y * 64;
  const f32x4 zf = {0.f, 0.f, 0.f, 0.f};
  f32x4 acc[4] = {zf, zf, zf, zf};
  const int lrow = tid >> 2, lk = (tid & 3) * 8;
  for (int k0 = 0; k0 < ND; k0 += 32) {
    __syncthreads();
    *(uint4*)(&As[lrow * LDSPAD + lk]) = *(const uint4*)(&A[(size_t)(m0 + lrow) * ND + k0 + lk]);
    *(uint4*)(&Bs[lrow * LDSPAD + lk]) = *(const uint4*)(&Bt[(size_t)(n0 + lrow) * ND + k0 + lk]);
    __syncthreads();
    bf16x8 af = *(const bf16x8*)(&As[(wave * 16 + col) * LDSPAD + quad * 8]);
    for (int nt = 0; nt < 4; nt++) {
      bf16x8 bfr = *(const bf16x8*)(&Bs[(nt * 16 + col) * LDSPAD + quad * 8]);
      acc[nt] = __builtin_amdgcn_mfma_f32_16x16x32_bf16(af, bfr, acc[nt], 0, 0, 0);
    }
  }
  for (int nt = 0; nt < 4; nt++) {
    const int n = n0 + nt * 16 + col;
    const float bvv = bias[n];
    for (int r = 0; r < 4; r++) {
      const int m = m0 + wave * 16 + quad * 4 + r;
      outp[(size_t)m * ND + n] = acc[nt][r] + bvv;
    }
  }
}

// -------- important-row attention: gathered rows, pure causal, 4-way strided key-split --------
// partials pbuf[((bh*4+chunk)*NILIST + row)*66] = {m, l, o[64] unnormalized}
__global__ __launch_bounds__(64) void csa_attn_imp(const u16* __restrict__ qb, const u16* __restrict__ kb,
                                                   const u16* __restrict__ vtb, const int* __restrict__ ilist,
                                                   float* __restrict__ pbuf) {
  const int lane = threadIdx.x;
  const int quad = lane >> 4, col = lane & 15;
  const int qt = blockIdx.x;     // 0..19
  const int chunk = blockIdx.y;  // 0..3
  const int bh = blockIdx.z;     // 0..15
  const int b = bh >> 3, h = bh & 7;

  const int* il = ilist + b * NILIST;
  const u16* qptr = qb + (size_t)(b * NH + h) * NS * NHD;
  const u16* kptr = kb + (size_t)(b * NH + h) * NS * NHD;
  const u16* vptr = vtb + (size_t)(b * NH + h) * NHD * NS;

  const int iq = il[qt * 16 + col];
  const int qrow = (iq < 0) ? 0 : iq;
  bf16x8 qf0 = *(const bf16x8*)(qptr + qrow * NHD + quad * 8);
  bf16x8 qf1 = *(const bf16x8*)(qptr + qrow * NHD + 32 + quad * 8);

  const f32x4 zf = {0.f, 0.f, 0.f, 0.f};
  float m_r[4], l_r[4];
  f32x4 of[4];
  int irow[4];
  for (int r = 0; r < 4; r++) {
    m_r[r] = -INFINITY;
    l_r[r] = 0.f;
    irow[r] = il[qt * 16 + quad * 4 + r];  // -1 for padding rows
  }
  for (int n = 0; n < 4; n++) of[n] = zf;

  __shared__ __attribute__((aligned(16))) u16 Pl[16 * LDSPAD];

  const int max_i = il[(qt * 16 + 15 > NKTOP - 1) ? (NKTOP - 1) : (qt * 16 + 15)];
  const int ntiles = (max_i >> 5) + 1;
  for (int t = chunk; t < ntiles; t += NCHUNK) {
    const int j0 = t * 32;
    f32x4 c0 = zf, c1 = zf;
    {
      bf16x8 k00 = *(const bf16x8*)(kptr + (j0 + col) * NHD + quad * 8);
      bf16x8 k01 = *(const bf16x8*)(kptr + (j0 + col) * NHD + 32 + quad * 8);
      c0 = __builtin_amdgcn_mfma_f32_16x16x32_bf16(qf0, k00, c0, 0, 0, 0);
      c0 = __builtin_amdgcn_mfma_f32_16x16x32_bf16(qf1, k01, c0, 0, 0, 0);
      bf16x8 k10 = *(const bf16x8*)(kptr + (j0 + 16 + col) * NHD + quad * 8);
      bf16x8 k11 = *(const bf16x8*)(kptr + (j0 + 16 + col) * NHD + 32 + quad * 8);
      c1 = __builtin_amdgcn_mfma_f32_16x16x32_bf16(qf0, k10, c1, 0, 0, 0);
      c1 = __builtin_amdgcn_mfma_f32_16x16x32_bf16(qf1, k11, c1, 0, 0, 0);
    }
    const int j_0 = j0 + col, j_1 = j0 + 16 + col;
    float p0s[4], p1s[4], alpha[4];
    for (int r = 0; r < 4; r++) {
      const int i = irow[r];
      float s0 = (j_0 <= i) ? c0[r] * 0.125f : -INFINITY;
      float s1 = (j_1 <= i) ? c1[r] * 0.125f : -INFINITY;
      float vmax = fmaxf(s0, s1);
      for (int off = 1; off < 16; off <<= 1) vmax = fmaxf(vmax, __shfl_xor(vmax, off, 64));
      float newm = fmaxf(m_r[r], vmax);
      bool dead = (newm == -INFINITY);
      float a = dead ? 1.f : __expf(m_r[r] - newm);
      float p0 = dead ? 0.f : __expf(s0 - newm);
      float p1 = dead ? 0.f : __expf(s1 - newm);
      float psum = p0 + p1;
      for (int off = 1; off < 16; off <<= 1) psum += __shfl_xor(psum, off, 64);
      m_r[r] = newm;
      l_r[r] = l_r[r] * a + psum;
      alpha[r] = a;
      p0s[r] = p0;
      p1s[r] = p1;
    }
    for (int n = 0; n < 4; n++)
      for (int r = 0; r < 4; r++) of[n][r] *= alpha[r];
    __syncthreads();
    for (int r = 0; r < 4; r++) {
      Pl[(quad * 4 + r) * LDSPAD + col] = f2bf(p0s[r]);
      Pl[(quad * 4 + r) * LDSPAD + 16 + col] = f2bf(p1s[r]);
    }
    __syncthreads();
    bf16x8 pf = *(const bf16x8*)(&Pl[col * LDSPAD + quad * 8]);
    for (int vn = 0; vn < 4; vn++) {
      bf16x8 vf = *(const bf16x8*)(vptr + (size_t)(vn * 16 + col) * NS + j0 + quad * 8);
      of[vn] = __builtin_amdgcn_mfma_f32_16x16x32_bf16(pf, vf, of[vn], 0, 0, 0);
    }
  }
  float* pr = pbuf + ((size_t)(bh * NCHUNK + chunk) * NILIST + qt * 16) * 66;
  for (int r = 0; r < 4; r++) {
    const int row = quad * 4 + r;
    if (col == 0) {
      pr[row * 66 + 0] = m_r[r];
      pr[row * 66 + 1] = l_r[r];
    }
    for (int vn = 0; vn < 4; vn++)
      pr[row * 66 + 2 + vn * 16 + col] = of[vn][r];
  }
}

// -------- merge important-row partials --------
__global__ __launch_bounds__(64) void csa_merge(const float* __restrict__ pbuf, const int* __restrict__ ilist,
                                                u16* __restrict__ attnb) {
  const int kp = blockIdx.x, h = blockIdx.y, b = blockIdx.z;
  const int lane = threadIdx.x;  // = d
  const int z = b * NH + h;
  float mc[NCHUNK], lc[NCHUNK], mstar = -INFINITY;
  for (int c = 0; c < NCHUNK; c++) {
    const float* base = pbuf + ((size_t)(z * NCHUNK + c) * NILIST + kp) * 66;
    mc[c] = base[0];
    lc[c] = base[1];
    mstar = fmaxf(mstar, mc[c]);
  }
  float lsum = 0.f, osum = 0.f;
  for (int c = 0; c < NCHUNK; c++) {
    const float* base = pbuf + ((size_t)(z * NCHUNK + c) * NILIST + kp) * 66;
    float w = (mc[c] == -INFINITY) ? 0.f : __expf(mc[c] - mstar);
    lsum += w * lc[c];
    osum += w * base[2 + lane];
  }
  const int i = ilist[b * NILIST + kp];
  attnb[((size_t)(b * NS + i) * NH + h) * NHD + lane] = f2bf(osum / lsum);
}

// -------- sparse-row attention: window + deduped random links, 1 wave per (row, head) --------
__global__ __launch_bounds__(256) void csa_attn_sparse(const u16* __restrict__ qb, const u16* __restrict__ kb,
                                                       const u16* __restrict__ vb, const int* __restrict__ rowimp,
                                                       const int* __restrict__ rand_idx, u16* __restrict__ attnb) {
  __shared__ __attribute__((aligned(16))) u16 ql[4][64];
  __shared__ float pl[4][64];
  __shared__ int jl[4][64];
  const int wave = threadIdx.x >> 6, lane = threadIdx.x & 63;
  const int i = blockIdx.x * 4 + wave;
  const int h = blockIdx.y, b = blockIdx.z;
  const int imp = rowimp[b * NS + i];

  const u16* qrow = qb + ((size_t)(b * NH + h) * NS + i) * NHD;
  const u16* kbase = kb + (size_t)(b * NH + h) * NS * NHD;
  const u16* vbase = vb + (size_t)(b * NH + h) * NS * NHD;

  // stage q into LDS (8 lanes x 16B)
  if (lane < 8) *(bf16x8*)(&ql[wave][lane * 8]) = *(const bf16x8*)(qrow + lane * 8);
  __syncthreads();

  // lane -> candidate key
  int j = 0, valid = 0;
  if (lane < 17) {
    j = i - NHWIN + lane;
    valid = (j >= 0);
  } else if (lane < 17 + NRC) {
    const int* rr = rand_idx + ((size_t)b * NS + i) * NRC;
    int c = lane - 17;
    j = rr[c];
    valid = (j <= i - NHWIN - 1);  // causal AND strictly below window
    for (int cp = 0; cp < c; cp++) valid &= (rr[cp] != j);  // first occurrence wins
  }
  const int jr = valid ? j : 0;

  // score = q . k[jr]
  float s = 0.f;
  const u16* krow = kbase + (size_t)jr * NHD;
  for (int c8 = 0; c8 < 8; c8++) {
    bf16x8 kv = *(const bf16x8*)(krow + c8 * 8);
    bf16x8 qv = *(const bf16x8*)(&ql[wave][c8 * 8]);
    for (int e = 0; e < 8; e++) s += bf2f(qv[e]) * bf2f(kv[e]);
  }
  s = valid ? s * 0.125f : -INFINITY;

  // softmax across wave
  float vmax = s;
  for (int off = 1; off < 64; off <<= 1) vmax = fmaxf(vmax, __shfl_xor(vmax, off, 64));
  float p = valid ? __expf(s - vmax) : 0.f;
  float lsum = p;
  for (int off = 1; off < 64; off <<= 1) lsum += __shfl_xor(lsum, off, 64);

  pl[wave][lane] = p;
  jl[wave][lane] = jr;
  __syncthreads();

  // PV: lane = output dim, coalesced V reads
  float o = 0.f;
  for (int jj = 0; jj < NKMAX; jj++) {
    float pj = pl[wave][jj];
    int jk = jl[wave][jj];
    o += pj * bf2f((short)vbase[(size_t)jk * NHD + lane]);
  }
  if (!imp)
    attnb[((size_t)(b * NS + i) * NH + h) * NHD + lane] = f2bf(o / lsum);
}

extern "C" void kernel_launch(void* const* d_in, const int* in_sizes, int n_in,
                              void* d_out, int out_size, void* d_ws, size_t ws_size,
                              hipStream_t stream) {
  const float* x = (const float*)d_in[0];
  const float* bq = (const float*)d_in[2];
  const float* bk = (const float*)d_in[4];
  const float* bv = (const float*)d_in[6];
  const float* bo = (const float*)d_in[8];
  const float* Ws1 = (const float*)d_in[9];
  const float* bs1 = (const float*)d_in[10];
  const float* Ws2 = (const float*)d_in[11];
  const int* rand_idx = (const int*)d_in[13];
  float* out = (float*)d_out;

  // workspace layout (~28 MB)
  char* p = (char*)d_ws;
  u16* wt = (u16*)p;         p += (size_t)4 * ND * ND * 2;         // 2 MB  [Wq^T;Wk^T;Wv^T;Wo^T] bf16
  u16* qbuf = (u16*)p;       p += (size_t)NB * NH * NS * NHD * 2;  // 4 MB [B,H,S,HD]
  u16* kbuf = (u16*)p;       p += (size_t)NB * NH * NS * NHD * 2;  // 4 MB
  u16* vtbuf = (u16*)p;      p += (size_t)NB * NH * NHD * NS * 2;  // 4 MB [B,H,HD,S]
  u16* vbuf = (u16*)p;       p += (size_t)NB * NH * NS * NHD * 2;  // 4 MB [B,H,S,HD]
  u16* attnb = (u16*)p;      p += (size_t)NB * NS * ND * 2;        // 4 MB [B,S,H,HD]
  float* logit = (float*)p;  p += (size_t)NB * NS * 4;
  int* rowimp = (int*)p;     p += (size_t)NB * NS * 4;
  int* ilist = (int*)p;      p += (size_t)NB * NILIST * 4;
  float* pbuf = (float*)p;   // 5.4 MB partials

  csa_cvt_w<<<dim3(16, 16, 4), 256, 0, stream>>>((const float*)d_in[1], (const float*)d_in[3],
                                                 (const float*)d_in[5], (const float*)d_in[7], wt);

  // scorer (fp32 exact ranking; sigmoid/bs2 dropped - rank-monotone)
  (void)hipMemsetAsync(logit, 0, (size_t)NB * NS * 4, stream);
  csa_scorer<<<dim3(NB * NS / 32, 4), 256, 0, stream>>>(x, Ws1, bs1, Ws2, logit);
  csa_rank<<<dim3(NS / 8, NB), 256, 0, stream>>>(logit, rowimp);
  csa_ilist<<<dim3(NB), 256, 0, stream>>>(rowimp, ilist);

  // fused QKV projection (reads fp32 x directly)
  csa_gemm_qkv<<<dim3(32, 24), 256, 0, stream>>>(x, wt, bq, bk, bv, qbuf, kbuf, vtbuf, vbuf);

  // attention: important rows (MFMA, split-K) + sparse rows (per-wave)
  csa_attn_imp<<<dim3(NILIST / 16, NCHUNK, NB * NH), 64, 0, stream>>>(qbuf, kbuf, vtbuf, ilist, pbuf);
  csa_attn_sparse<<<dim3(NS / 4, NH, NB), 256, 0, stream>>>(qbuf, kbuf, vbuf, rowimp, rand_idx, attnb);
  csa_merge<<<dim3(NKTOP, NH, NB), 64, 0, stream>>>(pbuf, ilist, attnb);

  // output projection
  csa_gemm_out<<<dim3(64, 8), 256, 0, stream>>>(attnb, wt + 3 * (size_t)ND * ND, bo, out);
}

// Round 5
// 213.111 us; speedup vs baseline: 1.7969x; 1.0341x over previous
//
#include <hip/hip_runtime.h>
#include <math.h>

typedef unsigned short u16;
typedef unsigned int u32;
typedef unsigned long long u64;
typedef short bf16x8 __attribute__((ext_vector_type(8)));
typedef float f32x4 __attribute__((ext_vector_type(4)));

constexpr int NB = 2, NS = 2048, ND = 512, NH = 8, NHD = 64;
constexpr int NKTOP = 307, NHWIN = 16, NRC = 16;
constexpr int NILIST = 320;        // 20 tiles of 16 (padded with -1)
constexpr int NSPAR = NS - NKTOP;  // 1741 non-important rows (exact: rank is a permutation)
constexpr int NSPAD = 1744;        // padded to multiple of 4
constexpr int NCHUNK = 4;          // key-split factor for important-row attention
constexpr int LDSPAD = 40;         // 80B row stride: breaks power-of-2 bank pattern, keeps 16B align

__device__ __forceinline__ u16 f2bf(float f) {
  u32 u = __builtin_bit_cast(u32, f);
  u32 r = (u + 0x7FFFu + ((u >> 16) & 1u)) >> 16;  // RNE
  return (u16)r;
}
__device__ __forceinline__ float bf2f(short v) {
  return __builtin_bit_cast(float, (u32)(u16)v << 16);
}

// -------- transpose + convert weights: W[K][N] fp32 -> Wt[N][K] bf16 (4 weights) --------
__global__ __launch_bounds__(256) void csa_cvt_w(const float* __restrict__ W0, const float* __restrict__ W1,
                                                 const float* __restrict__ W2, const float* __restrict__ W3,
                                                 u16* __restrict__ wt) {
  __shared__ float tile[32][33];
  int w = blockIdx.z;
  const float* src = (w == 0) ? W0 : (w == 1) ? W1 : (w == 2) ? W2 : W3;
  int kb = blockIdx.x * 32, nb = blockIdx.y * 32;
  int tx = threadIdx.x & 31, ty = threadIdx.x >> 5;
  for (int i = ty; i < 32; i += 8) tile[i][tx] = src[(size_t)(kb + i) * ND + nb + tx];
  __syncthreads();
  u16* dst = wt + (size_t)w * ND * ND;
  for (int i = ty; i < 32; i += 8) dst[(size_t)(nb + i) * ND + kb + tx] = f2bf(tile[tx][i]);
}

// -------- fused scorer: part[row][ny] = relu(x@Ws1+bs1).Ws2 over 64-col slice (fp32, no atomics) --------
// sigmoid and bs2 are strictly monotone / constant -> ranking on raw logits is identical.
__global__ __launch_bounds__(256) void csa_scorer(const float* __restrict__ x, const float* __restrict__ Ws1,
                                                  const float* __restrict__ bs1, const float* __restrict__ Ws2,
                                                  float* __restrict__ part) {
  __shared__ float As[32][33];  // [k][m]
  __shared__ float Bs[32][68];  // [k][n]
  const int tid = threadIdx.x;
  const int m0 = blockIdx.x * 32, n0 = blockIdx.y * 64;
  const int r2 = (tid >> 4) * 2;  // rows r2, r2+1
  const int c4 = (tid & 15) * 4;  // cols c4..c4+3
  float acc[2][4] = {};
  const int arow = tid & 31, aks = (tid >> 5) * 4;
  const int bk = tid >> 3, bc = (tid & 7) * 8;
  for (int k0 = 0; k0 < ND; k0 += 32) {
    __syncthreads();
    float4 av = *(const float4*)(&x[(size_t)(m0 + arow) * ND + k0 + aks]);
    As[aks + 0][arow] = av.x;
    As[aks + 1][arow] = av.y;
    As[aks + 2][arow] = av.z;
    As[aks + 3][arow] = av.w;
    *(float4*)(&Bs[bk][bc]) = *(const float4*)(&Ws1[(size_t)(k0 + bk) * 256 + n0 + bc]);
    *(float4*)(&Bs[bk][bc + 4]) = *(const float4*)(&Ws1[(size_t)(k0 + bk) * 256 + n0 + bc + 4]);
    __syncthreads();
    for (int k = 0; k < 32; k++) {
      float a0 = As[k][r2], a1 = As[k][r2 + 1];
      float4 b = *(const float4*)(&Bs[k][c4]);
      acc[0][0] += a0 * b.x; acc[0][1] += a0 * b.y; acc[0][2] += a0 * b.z; acc[0][3] += a0 * b.w;
      acc[1][0] += a1 * b.x; acc[1][1] += a1 * b.y; acc[1][2] += a1 * b.z; acc[1][3] += a1 * b.w;
    }
  }
  float4 w2 = *(const float4*)(&Ws2[n0 + c4]);
  float4 b1 = *(const float4*)(&bs1[n0 + c4]);
  float p0 = fmaxf(acc[0][0] + b1.x, 0.f) * w2.x + fmaxf(acc[0][1] + b1.y, 0.f) * w2.y +
             fmaxf(acc[0][2] + b1.z, 0.f) * w2.z + fmaxf(acc[0][3] + b1.w, 0.f) * w2.w;
  float p1 = fmaxf(acc[1][0] + b1.x, 0.f) * w2.x + fmaxf(acc[1][1] + b1.y, 0.f) * w2.y +
             fmaxf(acc[1][2] + b1.z, 0.f) * w2.z + fmaxf(acc[1][3] + b1.w, 0.f) * w2.w;
  for (int off = 1; off < 16; off <<= 1) {
    p0 += __shfl_xor(p0, off, 64);
    p1 += __shfl_xor(p1, off, 64);
  }
  if ((tid & 15) == 0) {
    part[(size_t)(m0 + r2) * 4 + blockIdx.y] = p0;
    part[(size_t)(m0 + r2 + 1) * 4 + blockIdx.y] = p1;
  }
}

// -------- exact top-k on logits (lax.top_k tie semantics: lower index wins), wave per 2 rows --------
__global__ __launch_bounds__(256) void csa_rank(const float* __restrict__ part, int* __restrict__ rowimp) {
  __shared__ float vals[NS];
  const int b = blockIdx.y;
  {
    int t8 = threadIdx.x * 8;
    for (int e = 0; e < 8; e++) {
      float4 pp = *(const float4*)(&part[(size_t)(b * NS + t8 + e) * 4]);
      vals[t8 + e] = (pp.x + pp.y) + (pp.z + pp.w);  // fixed order -> deterministic
    }
  }
  __syncthreads();
  const int wave = threadIdx.x >> 6, lane = threadIdx.x & 63;
  const int s0 = blockIdx.x * 8 + wave * 2;  // two rows per wave
  const int s1 = s0 + 1;
  const float v0 = vals[s0], v1 = vals[s1];
  int r0 = 0, r1 = 0;
  for (int t = lane; t < NS; t += 64) {
    float u = vals[t];
    r0 += (int)((u > v0) | ((u == v0) & (t < s0)));
    r1 += (int)((u > v1) | ((u == v1) & (t < s1)));
  }
  for (int off = 1; off < 64; off <<= 1) {
    r0 += __shfl_xor(r0, off, 64);
    r1 += __shfl_xor(r1, off, 64);
  }
  if (lane == 0) {
    rowimp[b * NS + s0] = (r0 < NKTOP) ? 1 : 0;
    rowimp[b * NS + s1] = (r1 < NKTOP) ? 1 : 0;
  }
}

// -------- compact important rows (and complement) into sorted lists --------
__global__ __launch_bounds__(256) void csa_ilist(const int* __restrict__ rowimp, int* __restrict__ ilist,
                                                 int* __restrict__ nlist) {
  __shared__ int cs[256];
  int b = blockIdx.x, t = threadIdx.x;
  int flags[8], sum = 0;
  for (int k = 0; k < 8; k++) {
    flags[k] = rowimp[b * NS + t * 8 + k];
    sum += flags[k];
  }
  cs[t] = sum;
  __syncthreads();
  for (int off = 1; off < 256; off <<= 1) {
    int v = (t >= off) ? cs[t - off] : 0;
    __syncthreads();
    cs[t] += v;
    __syncthreads();
  }
  int pos = cs[t] - sum;  // important rows before t*8
  for (int k = 0; k < 8; k++) {
    int r = t * 8 + k;
    if (flags[k]) ilist[b * NILIST + pos++] = r;
    else nlist[b * NSPAD + (r - pos)] = r;  // r - pos = non-important rows before r
  }
  if (t < NILIST - NKTOP) ilist[b * NILIST + NKTOP + t] = -1;
  if (t < NSPAD - NSPAR) nlist[b * NSPAD + NSPAR + t] = -1;
}

// -------- fused QKV projection: fp32 x staged->bf16, MFMA 128x64 tile, N=1536 --------
__global__ __launch_bounds__(256) void csa_gemm_qkv(const float* __restrict__ x, const u16* __restrict__ Bt,
                                                    const float* __restrict__ bq, const float* __restrict__ bk,
                                                    const float* __restrict__ bv, u16* __restrict__ qb,
                                                    u16* __restrict__ kb, u16* __restrict__ vtb,
                                                    u16* __restrict__ vb) {
  __shared__ __attribute__((aligned(16))) u16 As[128 * LDSPAD];
  __shared__ __attribute__((aligned(16))) u16 Bs[64 * LDSPAD];
  const int tid = threadIdx.x;
  const int wave = tid >> 6, lane = tid & 63;
  const int quad = lane >> 4, col = lane & 15;
  const int m0 = blockIdx.x * 128;
  const int n0 = blockIdx.y * 64;
  const f32x4 zf = {0.f, 0.f, 0.f, 0.f};
  f32x4 acc[2][4] = {{zf, zf, zf, zf}, {zf, zf, zf, zf}};
  const int sar = tid >> 1, sak = (tid & 1) * 16;  // A: 128 rows x 32 k
  const int sbr = tid >> 2, sbk = (tid & 3) * 8;   // B: 64 rows x 32 k
  for (int k0 = 0; k0 < ND; k0 += 32) {
    __syncthreads();
    {
      const float* xp = &x[(size_t)(m0 + sar) * ND + k0 + sak];
      float4 v0 = *(const float4*)(xp), v1 = *(const float4*)(xp + 4);
      float4 v2 = *(const float4*)(xp + 8), v3 = *(const float4*)(xp + 12);
      u32 w0 = (u32)f2bf(v0.x) | ((u32)f2bf(v0.y) << 16);
      u32 w1 = (u32)f2bf(v0.z) | ((u32)f2bf(v0.w) << 16);
      u32 w2 = (u32)f2bf(v1.x) | ((u32)f2bf(v1.y) << 16);
      u32 w3 = (u32)f2bf(v1.z) | ((u32)f2bf(v1.w) << 16);
      u32 w4 = (u32)f2bf(v2.x) | ((u32)f2bf(v2.y) << 16);
      u32 w5 = (u32)f2bf(v2.z) | ((u32)f2bf(v2.w) << 16);
      u32 w6 = (u32)f2bf(v3.x) | ((u32)f2bf(v3.y) << 16);
      u32 w7 = (u32)f2bf(v3.z) | ((u32)f2bf(v3.w) << 16);
      u32* ap = (u32*)&As[sar * LDSPAD + sak];
      ap[0] = w0; ap[1] = w1; ap[2] = w2; ap[3] = w3;
      ap[4] = w4; ap[5] = w5; ap[6] = w6; ap[7] = w7;
    }
    *(uint4*)(&Bs[sbr * LDSPAD + sbk]) = *(const uint4*)(&Bt[(size_t)(n0 + sbr) * ND + k0 + sbk]);
    __syncthreads();
    bf16x8 af0 = *(const bf16x8*)(&As[(wave * 32 + col) * LDSPAD + quad * 8]);
    bf16x8 af1 = *(const bf16x8*)(&As[(wave * 32 + 16 + col) * LDSPAD + quad * 8]);
    for (int c = 0; c < 4; c++) {
      bf16x8 bfr = *(const bf16x8*)(&Bs[(c * 16 + col) * LDSPAD + quad * 8]);
      acc[0][c] = __builtin_amdgcn_mfma_f32_16x16x32_bf16(af0, bfr, acc[0][c], 0, 0, 0);
      acc[1][c] = __builtin_amdgcn_mfma_f32_16x16x32_bf16(af1, bfr, acc[1][c], 0, 0, 0);
    }
  }
  const int w = n0 >> 9;  // 0=Q 1=K 2=V (uniform per block; 64-tiles align in 512 regions)
  const float* bias = (w == 0) ? bq : (w == 1) ? bk : bv;
  for (int c = 0; c < 4; c++) {
    const int ng = n0 + c * 16 + col;
    const int nn = ng & 511, hh = nn >> 6, hd = nn & 63;
    const float bvv = bias[nn];
    for (int r = 0; r < 2; r++) {
      for (int rr = 0; rr < 4; rr++) {
        const int m = m0 + wave * 32 + r * 16 + quad * 4 + rr;
        const int bb = m >> 11, s = m & (NS - 1);
        u16 v16 = f2bf(acc[r][c][rr] + bvv);
        if (w == 0) qb[((size_t)(bb * NH + hh) * NS + s) * NHD + hd] = v16;
        else if (w == 1) kb[((size_t)(bb * NH + hh) * NS + s) * NHD + hd] = v16;
        else {
          vtb[((size_t)(bb * NH + hh) * NHD + hd) * NS + s] = v16;
          vb[((size_t)(bb * NH + hh) * NS + s) * NHD + hd] = v16;
        }
      }
    }
  }
}

// -------- output projection: bf16 MFMA 64x64, fp32 out --------
__global__ __launch_bounds__(256) void csa_gemm_out(const u16* __restrict__ A, const u16* __restrict__ Bt,
                                                    const float* __restrict__ bias, float* __restrict__ outp) {
  __shared__ __attribute__((aligned(16))) u16 As[64 * LDSPAD];
  __shared__ __attribute__((aligned(16))) u16 Bs[64 * LDSPAD];
  const int tid = threadIdx.x;
  const int wave = tid >> 6, lane = tid & 63;
  const int quad = lane >> 4, col = lane & 15;
  const int m0 = blockIdx.x * 64;
  const int n0 = blockIdx.y * 64;
  const f32x4 zf = {0.f, 0.f, 0.f, 0.f};
  f32x4 acc[4] = {zf, zf, zf, zf};
  const int lrow = tid >> 2, lk = (tid & 3) * 8;
  for (int k0 = 0; k0 < ND; k0 += 32) {
    __syncthreads();
    *(uint4*)(&As[lrow * LDSPAD + lk]) = *(const uint4*)(&A[(size_t)(m0 + lrow) * ND + k0 + lk]);
    *(uint4*)(&Bs[lrow * LDSPAD + lk]) = *(const uint4*)(&Bt[(size_t)(n0 + lrow) * ND + k0 + lk]);
    __syncthreads();
    bf16x8 af = *(const bf16x8*)(&As[(wave * 16 + col) * LDSPAD + quad * 8]);
    for (int nt = 0; nt < 4; nt++) {
      bf16x8 bfr = *(const bf16x8*)(&Bs[(nt * 16 + col) * LDSPAD + quad * 8]);
      acc[nt] = __builtin_amdgcn_mfma_f32_16x16x32_bf16(af, bfr, acc[nt], 0, 0, 0);
    }
  }
  for (int nt = 0; nt < 4; nt++) {
    const int n = n0 + nt * 16 + col;
    const float bvv = bias[n];
    for (int r = 0; r < 4; r++) {
      const int m = m0 + wave * 16 + quad * 4 + r;
      outp[(size_t)m * ND + n] = acc[nt][r] + bvv;
    }
  }
}

// -------- important-row attention: gathered rows, pure causal, 4-way strided key-split --------
// partials pbuf[((bh*4+chunk)*NILIST + row)*66] = {m, l, o[64] unnormalized}
__global__ __launch_bounds__(64) void csa_attn_imp(const u16* __restrict__ qb, const u16* __restrict__ kb,
                                                   const u16* __restrict__ vtb, const int* __restrict__ ilist,
                                                   float* __restrict__ pbuf) {
  const int lane = threadIdx.x;
  const int quad = lane >> 4, col = lane & 15;
  const int qt = blockIdx.x;     // 0..19
  const int chunk = blockIdx.y;  // 0..3
  const int bh = blockIdx.z;     // 0..15
  const int b = bh >> 3, h = bh & 7;

  const int* il = ilist + b * NILIST;
  const u16* qptr = qb + (size_t)(b * NH + h) * NS * NHD;
  const u16* kptr = kb + (size_t)(b * NH + h) * NS * NHD;
  const u16* vptr = vtb + (size_t)(b * NH + h) * NHD * NS;

  const int iq = il[qt * 16 + col];
  const int qrow = (iq < 0) ? 0 : iq;
  bf16x8 qf0 = *(const bf16x8*)(qptr + qrow * NHD + quad * 8);
  bf16x8 qf1 = *(const bf16x8*)(qptr + qrow * NHD + 32 + quad * 8);

  const f32x4 zf = {0.f, 0.f, 0.f, 0.f};
  float m_r[4], l_r[4];
  f32x4 of[4];
  int irow[4];
  for (int r = 0; r < 4; r++) {
    m_r[r] = -INFINITY;
    l_r[r] = 0.f;
    irow[r] = il[qt * 16 + quad * 4 + r];  // -1 for padding rows
  }
  for (int n = 0; n < 4; n++) of[n] = zf;

  __shared__ __attribute__((aligned(16))) u16 Pl[16 * LDSPAD];

  const int max_i = il[(qt * 16 + 15 > NKTOP - 1) ? (NKTOP - 1) : (qt * 16 + 15)];
  const int ntiles = (max_i >> 5) + 1;
  for (int t = chunk; t < ntiles; t += NCHUNK) {
    const int j0 = t * 32;
    f32x4 c0 = zf, c1 = zf;
    {
      bf16x8 k00 = *(const bf16x8*)(kptr + (j0 + col) * NHD + quad * 8);
      bf16x8 k01 = *(const bf16x8*)(kptr + (j0 + col) * NHD + 32 + quad * 8);
      c0 = __builtin_amdgcn_mfma_f32_16x16x32_bf16(qf0, k00, c0, 0, 0, 0);
      c0 = __builtin_amdgcn_mfma_f32_16x16x32_bf16(qf1, k01, c0, 0, 0, 0);
      bf16x8 k10 = *(const bf16x8*)(kptr + (j0 + 16 + col) * NHD + quad * 8);
      bf16x8 k11 = *(const bf16x8*)(kptr + (j0 + 16 + col) * NHD + 32 + quad * 8);
      c1 = __builtin_amdgcn_mfma_f32_16x16x32_bf16(qf0, k10, c1, 0, 0, 0);
      c1 = __builtin_amdgcn_mfma_f32_16x16x32_bf16(qf1, k11, c1, 0, 0, 0);
    }
    const int j_0 = j0 + col, j_1 = j0 + 16 + col;
    float p0s[4], p1s[4], alpha[4];
    for (int r = 0; r < 4; r++) {
      const int i = irow[r];
      float s0 = (j_0 <= i) ? c0[r] * 0.125f : -INFINITY;
      float s1 = (j_1 <= i) ? c1[r] * 0.125f : -INFINITY;
      float vmax = fmaxf(s0, s1);
      for (int off = 1; off < 16; off <<= 1) vmax = fmaxf(vmax, __shfl_xor(vmax, off, 64));
      float newm = fmaxf(m_r[r], vmax);
      bool dead = (newm == -INFINITY);
      float a = dead ? 1.f : __expf(m_r[r] - newm);
      float p0 = dead ? 0.f : __expf(s0 - newm);
      float p1 = dead ? 0.f : __expf(s1 - newm);
      float psum = p0 + p1;
      for (int off = 1; off < 16; off <<= 1) psum += __shfl_xor(psum, off, 64);
      m_r[r] = newm;
      l_r[r] = l_r[r] * a + psum;
      alpha[r] = a;
      p0s[r] = p0;
      p1s[r] = p1;
    }
    for (int n = 0; n < 4; n++)
      for (int r = 0; r < 4; r++) of[n][r] *= alpha[r];
    __syncthreads();
    for (int r = 0; r < 4; r++) {
      Pl[(quad * 4 + r) * LDSPAD + col] = f2bf(p0s[r]);
      Pl[(quad * 4 + r) * LDSPAD + 16 + col] = f2bf(p1s[r]);
    }
    __syncthreads();
    bf16x8 pf = *(const bf16x8*)(&Pl[col * LDSPAD + quad * 8]);
    for (int vn = 0; vn < 4; vn++) {
      bf16x8 vf = *(const bf16x8*)(vptr + (size_t)(vn * 16 + col) * NS + j0 + quad * 8);
      of[vn] = __builtin_amdgcn_mfma_f32_16x16x32_bf16(pf, vf, of[vn], 0, 0, 0);
    }
  }
  float* pr = pbuf + ((size_t)(bh * NCHUNK + chunk) * NILIST + qt * 16) * 66;
  for (int r = 0; r < 4; r++) {
    const int row = quad * 4 + r;
    if (col == 0) {
      pr[row * 66 + 0] = m_r[r];
      pr[row * 66 + 1] = l_r[r];
    }
    for (int vn = 0; vn < 4; vn++)
      pr[row * 66 + 2 + vn * 16 + col] = of[vn][r];
  }
}

// -------- merge important-row partials --------
__global__ __launch_bounds__(64) void csa_merge(const float* __restrict__ pbuf, const int* __restrict__ ilist,
                                                u16* __restrict__ attnb) {
  const int kp = blockIdx.x, h = blockIdx.y, b = blockIdx.z;
  const int lane = threadIdx.x;  // = d
  const int z = b * NH + h;
  float mc[NCHUNK], lc[NCHUNK], mstar = -INFINITY;
  for (int c = 0; c < NCHUNK; c++) {
    const float* base = pbuf + ((size_t)(z * NCHUNK + c) * NILIST + kp) * 66;
    mc[c] = base[0];
    lc[c] = base[1];
    mstar = fmaxf(mstar, mc[c]);
  }
  float lsum = 0.f, osum = 0.f;
  for (int c = 0; c < NCHUNK; c++) {
    const float* base = pbuf + ((size_t)(z * NCHUNK + c) * NILIST + kp) * 66;
    float w = (mc[c] == -INFINITY) ? 0.f : __expf(mc[c] - mstar);
    lsum += w * lc[c];
    osum += w * base[2 + lane];
  }
  const int i = ilist[b * NILIST + kp];
  attnb[((size_t)(b * NS + i) * NH + h) * NHD + lane] = f2bf(osum / lsum);
}

// -------- sparse-row attention: non-important rows only, 2 lanes/key + diag, 1 wave/(row,head) --------
__global__ __launch_bounds__(256) void csa_attn_sparse(const u16* __restrict__ qb, const u16* __restrict__ kb,
                                                       const u16* __restrict__ vb, const int* __restrict__ nlist,
                                                       const int* __restrict__ rand_idx, u16* __restrict__ attnb) {
  __shared__ __attribute__((aligned(16))) u16 ql[4][64];
  __shared__ float pl[4][33];
  __shared__ int jl[4][33];
  const int wave = threadIdx.x >> 6, lane = threadIdx.x & 63;
  const int slot = blockIdx.x * 4 + wave;
  const int h = blockIdx.y, b = blockIdx.z;
  const int i = nlist[b * NSPAD + slot];  // -1 for the 3 pad slots
  const int iv = (i < 0) ? 0 : i;

  const u16* qrow = qb + ((size_t)(b * NH + h) * NS + iv) * NHD;
  const u16* kbase = kb + (size_t)(b * NH + h) * NS * NHD;
  const u16* vbase = vb + (size_t)(b * NH + h) * NS * NHD;

  // stage q into LDS (8 lanes x 16B)
  if (lane < 8) *(bf16x8*)(&ql[wave][lane * 8]) = *(const bf16x8*)(qrow + lane * 8);
  __syncthreads();

  // --- diagonal key j=i (always valid): lane = dim, full-wave reduce ---
  float sd = bf2f((short)ql[wave][lane]) * bf2f((short)kbase[(size_t)iv * NHD + lane]);
  for (int off = 1; off < 64; off <<= 1) sd += __shfl_xor(sd, off, 64);
  sd *= 0.125f;

  // --- 32 candidate keys, 2 lanes per key (half = 32 dims each) ---
  const int c = lane >> 1, half = lane & 1;
  int j, valid;
  if (c < 16) {
    j = i - NHWIN + c;  // window j = i-16 .. i-1
    valid = (j >= 0);
  } else {
    const int* rr = rand_idx + ((size_t)b * NS + iv) * NRC;
    const int cr = c - 16;
    j = rr[cr];
    valid = (j <= i - NHWIN - 1);  // causal AND strictly below window
    for (int cp = 0; cp < cr; cp++) valid &= (rr[cp] != j);  // first occurrence wins
  }
  const int jr = valid ? j : 0;
  float s = 0.f;
  {
    const u16* krow = kbase + (size_t)jr * NHD + half * 32;
    for (int c8 = 0; c8 < 4; c8++) {
      bf16x8 kv = *(const bf16x8*)(krow + c8 * 8);
      bf16x8 qv = *(const bf16x8*)(&ql[wave][half * 32 + c8 * 8]);
      for (int e = 0; e < 8; e++) s += bf2f(qv[e]) * bf2f(kv[e]);
    }
  }
  s += __shfl_xor(s, 1, 64);  // combine halves; both lanes of pair hold full dot
  s = valid ? s * 0.125f : -INFINITY;

  // --- softmax over {32 candidates} U {diag} ---
  float smax = s;
  for (int off = 1; off < 64; off <<= 1) smax = fmaxf(smax, __shfl_xor(smax, off, 64));
  smax = fmaxf(smax, sd);
  float p = valid ? __expf(s - smax) : 0.f;
  float pd = __expf(sd - smax);
  float pm = (half == 0) ? p : 0.f;
  for (int off = 1; off < 64; off <<= 1) pm += __shfl_xor(pm, off, 64);
  const float lsum = pm + pd;

  if (half == 0) {
    pl[wave][c] = p;
    jl[wave][c] = jr;
  }
  if (lane == 0) {
    pl[wave][32] = pd;
    jl[wave][32] = iv;
  }
  __syncthreads();

  // --- PV: lane = output dim; key index is wave-uniform -> SGPR base via readfirstlane ---
  float o = 0.f;
  for (int jj = 0; jj < 33; jj++) {
    const int jk = __builtin_amdgcn_readfirstlane(jl[wave][jj]);
    const float pj = pl[wave][jj];
    o += pj * bf2f((short)vbase[(size_t)jk * NHD + lane]);
  }
  if (i >= 0)
    attnb[((size_t)(b * NS + i) * NH + h) * NHD + lane] = f2bf(o / lsum);
}

extern "C" void kernel_launch(void* const* d_in, const int* in_sizes, int n_in,
                              void* d_out, int out_size, void* d_ws, size_t ws_size,
                              hipStream_t stream) {
  const float* x = (const float*)d_in[0];
  const float* bq = (const float*)d_in[2];
  const float* bk = (const float*)d_in[4];
  const float* bv = (const float*)d_in[6];
  const float* bo = (const float*)d_in[8];
  const float* Ws1 = (const float*)d_in[9];
  const float* bs1 = (const float*)d_in[10];
  const float* Ws2 = (const float*)d_in[11];
  const int* rand_idx = (const int*)d_in[13];
  float* out = (float*)d_out;

  // workspace layout (~28 MB)
  char* p = (char*)d_ws;
  u16* wt = (u16*)p;         p += (size_t)4 * ND * ND * 2;         // 2 MB  [Wq^T;Wk^T;Wv^T;Wo^T] bf16
  u16* qbuf = (u16*)p;       p += (size_t)NB * NH * NS * NHD * 2;  // 4 MB [B,H,S,HD]
  u16* kbuf = (u16*)p;       p += (size_t)NB * NH * NS * NHD * 2;  // 4 MB
  u16* vtbuf = (u16*)p;      p += (size_t)NB * NH * NHD * NS * 2;  // 4 MB [B,H,HD,S]
  u16* vbuf = (u16*)p;       p += (size_t)NB * NH * NS * NHD * 2;  // 4 MB [B,H,S,HD]
  u16* attnb = (u16*)p;      p += (size_t)NB * NS * ND * 2;        // 4 MB [B,S,H,HD]
  float* part = (float*)p;   p += (size_t)NB * NS * 4 * 4;         // 64 KB logit partials
  int* rowimp = (int*)p;     p += (size_t)NB * NS * 4;
  int* ilist = (int*)p;      p += (size_t)NB * NILIST * 4;
  int* nlist = (int*)p;      p += (size_t)NB * NSPAD * 4;
  float* pbuf = (float*)p;   // 5.4 MB partials

  csa_cvt_w<<<dim3(16, 16, 4), 256, 0, stream>>>((const float*)d_in[1], (const float*)d_in[3],
                                                 (const float*)d_in[5], (const float*)d_in[7], wt);

  // scorer (fp32 exact ranking; sigmoid/bs2 dropped - rank-monotone; no atomics)
  csa_scorer<<<dim3(NB * NS / 32, 4), 256, 0, stream>>>(x, Ws1, bs1, Ws2, part);
  csa_rank<<<dim3(NS / 8, NB), 256, 0, stream>>>(part, rowimp);
  csa_ilist<<<dim3(NB), 256, 0, stream>>>(rowimp, ilist, nlist);

  // fused QKV projection (reads fp32 x directly)
  csa_gemm_qkv<<<dim3(32, 24), 256, 0, stream>>>(x, wt, bq, bk, bv, qbuf, kbuf, vtbuf, vbuf);

  // attention: important rows (MFMA, split-K) + sparse rows (per-wave, complement list)
  csa_attn_imp<<<dim3(NILIST / 16, NCHUNK, NB * NH), 64, 0, stream>>>(qbuf, kbuf, vtbuf, ilist, pbuf);
  csa_attn_sparse<<<dim3(NSPAD / 4, NH, NB), 256, 0, stream>>>(qbuf, kbuf, vbuf, nlist, rand_idx, attnb);
  csa_merge<<<dim3(NKTOP, NH, NB), 64, 0, stream>>>(pbuf, ilist, attnb);

  // output projection
  csa_gemm_out<<<dim3(64, 8), 256, 0, stream>>>(attnb, wt + 3 * (size_t)ND * ND, bo, out);
}

// Round 6
// 209.465 us; speedup vs baseline: 1.8282x; 1.0174x over previous
//
#include <hip/hip_runtime.h>
#include <math.h>

typedef unsigned short u16;
typedef unsigned int u32;
typedef unsigned long long u64;
typedef short bf16x8 __attribute__((ext_vector_type(8)));
typedef float f32x4 __attribute__((ext_vector_type(4)));

constexpr int NB = 2, NS = 2048, ND = 512, NH = 8, NHD = 64;
constexpr int NKTOP = 307, NHWIN = 16, NRC = 16;
constexpr int NILIST = 320;        // 20 tiles of 16 (padded with -1)
constexpr int NSPAR = NS - NKTOP;  // 1741 non-important rows (exact: rank is a permutation)
constexpr int NSPAD = 1744;        // padded to multiple of 4
constexpr int NCHUNK = 8;          // key-split factor for important-row attention
constexpr int LDSPAD = 40;         // 80B row stride for 32-k tiles
constexpr int LDSK64 = 72;         // 144B row stride for 64-k tiles
constexpr int PSTR = 72;           // P-tile row stride (16 rows x 64 keys)

__device__ __forceinline__ u16 f2bf(float f) {
  u32 u = __builtin_bit_cast(u32, f);
  u32 r = (u + 0x7FFFu + ((u >> 16) & 1u)) >> 16;  // RNE
  return (u16)r;
}
__device__ __forceinline__ float bf2f(short v) {
  return __builtin_bit_cast(float, (u32)(u16)v << 16);
}

// -------- transpose + convert weights: W[K][N] fp32 -> Wt[N][K] bf16, 128B packed writes --------
__global__ __launch_bounds__(256) void csa_cvt_w(const float* __restrict__ W0, const float* __restrict__ W1,
                                                 const float* __restrict__ W2, const float* __restrict__ W3,
                                                 u16* __restrict__ wt) {
  __shared__ float tile[64][33];
  int w = blockIdx.z;
  const float* src = (w == 0) ? W0 : (w == 1) ? W1 : (w == 2) ? W2 : W3;
  int kb = blockIdx.x * 64, nb = blockIdx.y * 32;
  int tx = threadIdx.x & 31, ty = threadIdx.x >> 5;
  for (int i = ty; i < 64; i += 8) tile[i][tx] = src[(size_t)(kb + i) * ND + nb + tx];
  __syncthreads();
  u16* dst = wt + (size_t)w * ND * ND;
  for (int n = ty; n < 32; n += 8) {
    u32 pk = (u32)f2bf(tile[2 * tx][n]) | ((u32)f2bf(tile[2 * tx + 1][n]) << 16);
    *(u32*)(&dst[(size_t)(nb + n) * ND + kb + 2 * tx]) = pk;
  }
}

// -------- fused scorer: part[row][ny] = relu(x@Ws1+bs1).Ws2 over 64-col slice (fp32) --------
// sigmoid and bs2 are strictly monotone / constant -> ranking on raw logits is identical.
__global__ __launch_bounds__(256) void csa_scorer(const float* __restrict__ x, const float* __restrict__ Ws1,
                                                  const float* __restrict__ bs1, const float* __restrict__ Ws2,
                                                  float* __restrict__ part) {
  __shared__ float As[32][68];  // [k][m], 64 m
  __shared__ float Bs[32][68];  // [k][n], 64 n
  const int tid = threadIdx.x;
  const int m0 = blockIdx.x * 64, n0 = blockIdx.y * 64;
  const int ty = tid >> 4, tx = tid & 15;  // rows ty*4.., cols tx*4..
  float acc[4][4] = {};
  const int arow = tid & 63, aks = (tid >> 6) * 8;
  const int bk = tid >> 3, bc = (tid & 7) * 8;
  for (int k0 = 0; k0 < ND; k0 += 32) {
    __syncthreads();
    {
      float4 a0 = *(const float4*)(&x[(size_t)(m0 + arow) * ND + k0 + aks]);
      float4 a1 = *(const float4*)(&x[(size_t)(m0 + arow) * ND + k0 + aks + 4]);
      As[aks + 0][arow] = a0.x; As[aks + 1][arow] = a0.y;
      As[aks + 2][arow] = a0.z; As[aks + 3][arow] = a0.w;
      As[aks + 4][arow] = a1.x; As[aks + 5][arow] = a1.y;
      As[aks + 6][arow] = a1.z; As[aks + 7][arow] = a1.w;
    }
    *(float4*)(&Bs[bk][bc]) = *(const float4*)(&Ws1[(size_t)(k0 + bk) * 256 + n0 + bc]);
    *(float4*)(&Bs[bk][bc + 4]) = *(const float4*)(&Ws1[(size_t)(k0 + bk) * 256 + n0 + bc + 4]);
    __syncthreads();
    for (int k = 0; k < 32; k++) {
      float4 av = *(const float4*)(&As[k][ty * 4]);
      float4 bv = *(const float4*)(&Bs[k][tx * 4]);
      float aa[4] = {av.x, av.y, av.z, av.w};
      float bb[4] = {bv.x, bv.y, bv.z, bv.w};
      for (int i = 0; i < 4; i++)
        for (int j = 0; j < 4; j++)
          acc[i][j] += aa[i] * bb[j];
    }
  }
  float4 w2 = *(const float4*)(&Ws2[n0 + tx * 4]);
  float4 b1 = *(const float4*)(&bs1[n0 + tx * 4]);
  for (int i = 0; i < 4; i++) {
    float p = fmaxf(acc[i][0] + b1.x, 0.f) * w2.x + fmaxf(acc[i][1] + b1.y, 0.f) * w2.y +
              fmaxf(acc[i][2] + b1.z, 0.f) * w2.z + fmaxf(acc[i][3] + b1.w, 0.f) * w2.w;
    for (int off = 1; off < 16; off <<= 1) p += __shfl_xor(p, off, 64);
    if (tx == 0) part[(size_t)(m0 + ty * 4 + i) * 4 + blockIdx.y] = p;
  }
}

// -------- exact top-k on logits (lax.top_k tie semantics: lower index wins), wave per 2 rows --------
__global__ __launch_bounds__(256) void csa_rank(const float* __restrict__ part, int* __restrict__ rowimp) {
  __shared__ float vals[NS];
  const int b = blockIdx.y;
  {
    int t8 = threadIdx.x * 8;
    for (int e = 0; e < 8; e++) {
      float4 pp = *(const float4*)(&part[(size_t)(b * NS + t8 + e) * 4]);
      vals[t8 + e] = (pp.x + pp.y) + (pp.z + pp.w);  // fixed order -> deterministic
    }
  }
  __syncthreads();
  const int wave = threadIdx.x >> 6, lane = threadIdx.x & 63;
  const int s0 = blockIdx.x * 8 + wave * 2;  // two rows per wave
  const int s1 = s0 + 1;
  const float v0 = vals[s0], v1 = vals[s1];
  int r0 = 0, r1 = 0;
  for (int t = lane; t < NS; t += 64) {
    float u = vals[t];
    r0 += (int)((u > v0) | ((u == v0) & (t < s0)));
    r1 += (int)((u > v1) | ((u == v1) & (t < s1)));
  }
  for (int off = 1; off < 64; off <<= 1) {
    r0 += __shfl_xor(r0, off, 64);
    r1 += __shfl_xor(r1, off, 64);
  }
  if (lane == 0) {
    rowimp[b * NS + s0] = (r0 < NKTOP) ? 1 : 0;
    rowimp[b * NS + s1] = (r1 < NKTOP) ? 1 : 0;
  }
}

// -------- compact important rows (and complement) into sorted lists --------
__global__ __launch_bounds__(256) void csa_ilist(const int* __restrict__ rowimp, int* __restrict__ ilist,
                                                 int* __restrict__ nlist) {
  __shared__ int cs[256];
  int b = blockIdx.x, t = threadIdx.x;
  int flags[8], sum = 0;
  for (int k = 0; k < 8; k++) {
    flags[k] = rowimp[b * NS + t * 8 + k];
    sum += flags[k];
  }
  cs[t] = sum;
  __syncthreads();
  for (int off = 1; off < 256; off <<= 1) {
    int v = (t >= off) ? cs[t - off] : 0;
    __syncthreads();
    cs[t] += v;
    __syncthreads();
  }
  int pos = cs[t] - sum;  // important rows before t*8
  for (int k = 0; k < 8; k++) {
    int r = t * 8 + k;
    if (flags[k]) ilist[b * NILIST + pos++] = r;
    else nlist[b * NSPAD + (r - pos)] = r;  // r - pos = non-important rows before r
  }
  if (t < NILIST - NKTOP) ilist[b * NILIST + NKTOP + t] = -1;
  if (t < NSPAD - NSPAR) nlist[b * NSPAD + NSPAR + t] = -1;
}

// -------- fused QKV projection: fp32 x staged->bf16, MFMA 128x64 tile, N=1536 --------
__global__ __launch_bounds__(256) void csa_gemm_qkv(const float* __restrict__ x, const u16* __restrict__ Bt,
                                                    const float* __restrict__ bq, const float* __restrict__ bk,
                                                    const float* __restrict__ bv, u16* __restrict__ qb,
                                                    u16* __restrict__ kb, u16* __restrict__ vtb,
                                                    u16* __restrict__ vb) {
  __shared__ __attribute__((aligned(16))) u16 As[128 * LDSPAD];
  __shared__ __attribute__((aligned(16))) u16 Bs[64 * LDSPAD];
  const int tid = threadIdx.x;
  const int wave = tid >> 6, lane = tid & 63;
  const int quad = lane >> 4, col = lane & 15;
  const int m0 = blockIdx.x * 128;
  const int n0 = blockIdx.y * 64;
  const f32x4 zf = {0.f, 0.f, 0.f, 0.f};
  f32x4 acc[2][4] = {{zf, zf, zf, zf}, {zf, zf, zf, zf}};
  const int sar = tid >> 1, sak = (tid & 1) * 16;  // A: 128 rows x 32 k
  const int sbr = tid >> 2, sbk = (tid & 3) * 8;   // B: 64 rows x 32 k
  for (int k0 = 0; k0 < ND; k0 += 32) {
    __syncthreads();
    {
      const float* xp = &x[(size_t)(m0 + sar) * ND + k0 + sak];
      float4 v0 = *(const float4*)(xp), v1 = *(const float4*)(xp + 4);
      float4 v2 = *(const float4*)(xp + 8), v3 = *(const float4*)(xp + 12);
      u32 w0 = (u32)f2bf(v0.x) | ((u32)f2bf(v0.y) << 16);
      u32 w1 = (u32)f2bf(v0.z) | ((u32)f2bf(v0.w) << 16);
      u32 w2 = (u32)f2bf(v1.x) | ((u32)f2bf(v1.y) << 16);
      u32 w3 = (u32)f2bf(v1.z) | ((u32)f2bf(v1.w) << 16);
      u32 w4 = (u32)f2bf(v2.x) | ((u32)f2bf(v2.y) << 16);
      u32 w5 = (u32)f2bf(v2.z) | ((u32)f2bf(v2.w) << 16);
      u32 w6 = (u32)f2bf(v3.x) | ((u32)f2bf(v3.y) << 16);
      u32 w7 = (u32)f2bf(v3.z) | ((u32)f2bf(v3.w) << 16);
      u32* ap = (u32*)&As[sar * LDSPAD + sak];
      ap[0] = w0; ap[1] = w1; ap[2] = w2; ap[3] = w3;
      ap[4] = w4; ap[5] = w5; ap[6] = w6; ap[7] = w7;
    }
    *(uint4*)(&Bs[sbr * LDSPAD + sbk]) = *(const uint4*)(&Bt[(size_t)(n0 + sbr) * ND + k0 + sbk]);
    __syncthreads();
    bf16x8 af0 = *(const bf16x8*)(&As[(wave * 32 + col) * LDSPAD + quad * 8]);
    bf16x8 af1 = *(const bf16x8*)(&As[(wave * 32 + 16 + col) * LDSPAD + quad * 8]);
    for (int c = 0; c < 4; c++) {
      bf16x8 bfr = *(const bf16x8*)(&Bs[(c * 16 + col) * LDSPAD + quad * 8]);
      acc[0][c] = __builtin_amdgcn_mfma_f32_16x16x32_bf16(af0, bfr, acc[0][c], 0, 0, 0);
      acc[1][c] = __builtin_amdgcn_mfma_f32_16x16x32_bf16(af1, bfr, acc[1][c], 0, 0, 0);
    }
  }
  const int w = n0 >> 9;  // 0=Q 1=K 2=V (uniform per block; 64-tiles align in 512 regions)
  const float* bias = (w == 0) ? bq : (w == 1) ? bk : bv;
  for (int c = 0; c < 4; c++) {
    const int ng = n0 + c * 16 + col;
    const int nn = ng & 511, hh = nn >> 6, hd = nn & 63;
    const float bvv = bias[nn];
    for (int r = 0; r < 2; r++) {
      for (int rr = 0; rr < 4; rr++) {
        const int m = m0 + wave * 32 + r * 16 + quad * 4 + rr;
        const int bb = m >> 11, s = m & (NS - 1);
        u16 v16 = f2bf(acc[r][c][rr] + bvv);
        if (w == 0) qb[((size_t)(bb * NH + hh) * NS + s) * NHD + hd] = v16;
        else if (w == 1) kb[((size_t)(bb * NH + hh) * NS + s) * NHD + hd] = v16;
        else {
          vtb[((size_t)(bb * NH + hh) * NHD + hd) * NS + s] = v16;
          vb[((size_t)(bb * NH + hh) * NS + s) * NHD + hd] = v16;
        }
      }
    }
  }
}

// -------- output projection: bf16 MFMA 64x64 tile, K=64 stages (half the barriers), fp32 out --------
__global__ __launch_bounds__(256) void csa_gemm_out(const u16* __restrict__ A, const u16* __restrict__ Bt,
                                                    const float* __restrict__ bias, float* __restrict__ outp) {
  __shared__ __attribute__((aligned(16))) u16 As[64 * LDSK64];
  __shared__ __attribute__((aligned(16))) u16 Bs[64 * LDSK64];
  const int tid = threadIdx.x;
  const int wave = tid >> 6, lane = tid & 63;
  const int quad = lane >> 4, col = lane & 15;
  const int m0 = blockIdx.x * 64;
  const int n0 = blockIdx.y * 64;
  const f32x4 zf = {0.f, 0.f, 0.f, 0.f};
  f32x4 acc[4] = {zf, zf, zf, zf};
  const int sr = tid >> 2, sk = (tid & 3) * 16;  // 64 rows x 64 k, 16 u16/thread
  for (int k0 = 0; k0 < ND; k0 += 64) {
    __syncthreads();
    *(uint4*)(&As[sr * LDSK64 + sk]) = *(const uint4*)(&A[(size_t)(m0 + sr) * ND + k0 + sk]);
    *(uint4*)(&As[sr * LDSK64 + sk + 8]) = *(const uint4*)(&A[(size_t)(m0 + sr) * ND + k0 + sk + 8]);
    *(uint4*)(&Bs[sr * LDSK64 + sk]) = *(const uint4*)(&Bt[(size_t)(n0 + sr) * ND + k0 + sk]);
    *(uint4*)(&Bs[sr * LDSK64 + sk + 8]) = *(const uint4*)(&Bt[(size_t)(n0 + sr) * ND + k0 + sk + 8]);
    __syncthreads();
    bf16x8 af0 = *(const bf16x8*)(&As[(wave * 16 + col) * LDSK64 + quad * 8]);
    bf16x8 af1 = *(const bf16x8*)(&As[(wave * 16 + col) * LDSK64 + 32 + quad * 8]);
    for (int nt = 0; nt < 4; nt++) {
      bf16x8 bf0 = *(const bf16x8*)(&Bs[(nt * 16 + col) * LDSK64 + quad * 8]);
      bf16x8 bf1 = *(const bf16x8*)(&Bs[(nt * 16 + col) * LDSK64 + 32 + quad * 8]);
      acc[nt] = __builtin_amdgcn_mfma_f32_16x16x32_bf16(af0, bf0, acc[nt], 0, 0, 0);
      acc[nt] = __builtin_amdgcn_mfma_f32_16x16x32_bf16(af1, bf1, acc[nt], 0, 0, 0);
    }
  }
  for (int nt = 0; nt < 4; nt++) {
    const int n = n0 + nt * 16 + col;
    const float bvv = bias[n];
    for (int r = 0; r < 4; r++) {
      const int m = m0 + wave * 16 + quad * 4 + r;
      outp[(size_t)m * ND + n] = acc[nt][r] + bvv;
    }
  }
}

// -------- important-row attention: gathered rows, pure causal, 8-way key-split, 64-key tiles --------
// partials pbuf[((bh*8+chunk)*NILIST + row)*66] = {m, l, o[64] unnormalized}
__global__ __launch_bounds__(64) void csa_attn_imp(const u16* __restrict__ qb, const u16* __restrict__ kb,
                                                   const u16* __restrict__ vtb, const int* __restrict__ ilist,
                                                   float* __restrict__ pbuf) {
  const int lane = threadIdx.x;
  const int quad = lane >> 4, col = lane & 15;
  const int qt = blockIdx.x;     // 0..19
  const int chunk = blockIdx.y;  // 0..7
  const int bh = blockIdx.z;     // 0..15
  const int b = bh >> 3, h = bh & 7;

  const int* il = ilist + b * NILIST;
  const u16* qptr = qb + (size_t)(b * NH + h) * NS * NHD;
  const u16* kptr = kb + (size_t)(b * NH + h) * NS * NHD;
  const u16* vptr = vtb + (size_t)(b * NH + h) * NHD * NS;

  const int iq = il[qt * 16 + col];
  const int qrow = (iq < 0) ? 0 : iq;
  bf16x8 qf0 = *(const bf16x8*)(qptr + qrow * NHD + quad * 8);
  bf16x8 qf1 = *(const bf16x8*)(qptr + qrow * NHD + 32 + quad * 8);

  const f32x4 zf = {0.f, 0.f, 0.f, 0.f};
  float m_r[4], l_r[4];
  f32x4 of[4];
  int irow[4];
  for (int r = 0; r < 4; r++) {
    m_r[r] = -INFINITY;
    l_r[r] = 0.f;
    irow[r] = il[qt * 16 + quad * 4 + r];  // -1 for padding rows
  }
  for (int n = 0; n < 4; n++) of[n] = zf;

  __shared__ __attribute__((aligned(16))) u16 Pl[16 * PSTR];

  const int max_i = il[(qt * 16 + 15 > NKTOP - 1) ? (NKTOP - 1) : (qt * 16 + 15)];
  const int ntiles = (max_i >> 6) + 1;  // 64-key tiles
  for (int t = chunk; t < ntiles; t += NCHUNK) {
    const int j0 = t * 64;
    f32x4 cg[4];
    for (int g = 0; g < 4; g++) {
      const int jb = j0 + g * 16;
      bf16x8 k0f = *(const bf16x8*)(kptr + (jb + col) * NHD + quad * 8);
      bf16x8 k1f = *(const bf16x8*)(kptr + (jb + col) * NHD + 32 + quad * 8);
      f32x4 c = zf;
      c = __builtin_amdgcn_mfma_f32_16x16x32_bf16(qf0, k0f, c, 0, 0, 0);
      c = __builtin_amdgcn_mfma_f32_16x16x32_bf16(qf1, k1f, c, 0, 0, 0);
      cg[g] = c;
    }
    float ps[4][4], alpha[4];
    for (int r = 0; r < 4; r++) {
      const int i = irow[r];
      float s[4];
      float vmax = -INFINITY;
      for (int g = 0; g < 4; g++) {
        s[g] = (j0 + g * 16 + col <= i) ? cg[g][r] * 0.125f : -INFINITY;
        vmax = fmaxf(vmax, s[g]);
      }
      for (int off = 1; off < 16; off <<= 1) vmax = fmaxf(vmax, __shfl_xor(vmax, off, 64));
      float newm = fmaxf(m_r[r], vmax);
      bool dead = (newm == -INFINITY);
      float a = dead ? 1.f : __expf(m_r[r] - newm);
      float psum = 0.f;
      for (int g = 0; g < 4; g++) {
        float p = dead ? 0.f : __expf(s[g] - newm);
        ps[r][g] = p;
        psum += p;
      }
      for (int off = 1; off < 16; off <<= 1) psum += __shfl_xor(psum, off, 64);
      m_r[r] = newm;
      l_r[r] = l_r[r] * a + psum;
      alpha[r] = a;
    }
    for (int n = 0; n < 4; n++)
      for (int r = 0; r < 4; r++) of[n][r] *= alpha[r];
    __syncthreads();
    for (int r = 0; r < 4; r++)
      for (int g = 0; g < 4; g++)
        Pl[(quad * 4 + r) * PSTR + g * 16 + col] = f2bf(ps[r][g]);
    __syncthreads();
    bf16x8 pf0 = *(const bf16x8*)(&Pl[col * PSTR + quad * 8]);
    bf16x8 pf1 = *(const bf16x8*)(&Pl[col * PSTR + 32 + quad * 8]);
    for (int vn = 0; vn < 4; vn++) {
      bf16x8 vf0 = *(const bf16x8*)(vptr + (size_t)(vn * 16 + col) * NS + j0 + quad * 8);
      bf16x8 vf1 = *(const bf16x8*)(vptr + (size_t)(vn * 16 + col) * NS + j0 + 32 + quad * 8);
      of[vn] = __builtin_amdgcn_mfma_f32_16x16x32_bf16(pf0, vf0, of[vn], 0, 0, 0);
      of[vn] = __builtin_amdgcn_mfma_f32_16x16x32_bf16(pf1, vf1, of[vn], 0, 0, 0);
    }
  }
  float* pr = pbuf + ((size_t)(bh * NCHUNK + chunk) * NILIST + qt * 16) * 66;
  for (int r = 0; r < 4; r++) {
    const int row = quad * 4 + r;
    if (col == 0) {
      pr[row * 66 + 0] = m_r[r];
      pr[row * 66 + 1] = l_r[r];
    }
    for (int vn = 0; vn < 4; vn++)
      pr[row * 66 + 2 + vn * 16 + col] = of[vn][r];
  }
}

// -------- merge important-row partials --------
__global__ __launch_bounds__(64) void csa_merge(const float* __restrict__ pbuf, const int* __restrict__ ilist,
                                                u16* __restrict__ attnb) {
  const int kp = blockIdx.x, h = blockIdx.y, b = blockIdx.z;
  const int lane = threadIdx.x;  // = d
  const int z = b * NH + h;
  float mc[NCHUNK], lc[NCHUNK], mstar = -INFINITY;
  for (int c = 0; c < NCHUNK; c++) {
    const float* base = pbuf + ((size_t)(z * NCHUNK + c) * NILIST + kp) * 66;
    mc[c] = base[0];
    lc[c] = base[1];
    mstar = fmaxf(mstar, mc[c]);
  }
  float lsum = 0.f, osum = 0.f;
  for (int c = 0; c < NCHUNK; c++) {
    const float* base = pbuf + ((size_t)(z * NCHUNK + c) * NILIST + kp) * 66;
    float w = (mc[c] == -INFINITY) ? 0.f : __expf(mc[c] - mstar);
    lsum += w * lc[c];
    osum += w * base[2 + lane];
  }
  const int i = ilist[b * NILIST + kp];
  attnb[((size_t)(b * NS + i) * NH + h) * NHD + lane] = f2bf(osum / lsum);
}

// -------- sparse-row attention: non-important rows only, 2 lanes/key + diag, 1 wave/(row,head) --------
__global__ __launch_bounds__(256) void csa_attn_sparse(const u16* __restrict__ qb, const u16* __restrict__ kb,
                                                       const u16* __restrict__ vb, const int* __restrict__ nlist,
                                                       const int* __restrict__ rand_idx, u16* __restrict__ attnb) {
  __shared__ __attribute__((aligned(16))) u16 ql[4][64];
  __shared__ float pl[4][33];
  __shared__ int jl[4][33];
  const int wave = threadIdx.x >> 6, lane = threadIdx.x & 63;
  const int slot = blockIdx.x * 4 + wave;
  const int h = blockIdx.y, b = blockIdx.z;
  const int i = nlist[b * NSPAD + slot];  // -1 for the 3 pad slots
  const int iv = (i < 0) ? 0 : i;

  const u16* qrow = qb + ((size_t)(b * NH + h) * NS + iv) * NHD;
  const u16* kbase = kb + (size_t)(b * NH + h) * NS * NHD;
  const u16* vbase = vb + (size_t)(b * NH + h) * NS * NHD;

  // stage q into LDS (8 lanes x 16B)
  if (lane < 8) *(bf16x8*)(&ql[wave][lane * 8]) = *(const bf16x8*)(qrow + lane * 8);
  __syncthreads();

  // --- diagonal key j=i (always valid): lane = dim, full-wave reduce ---
  float sd = bf2f((short)ql[wave][lane]) * bf2f((short)kbase[(size_t)iv * NHD + lane]);
  for (int off = 1; off < 64; off <<= 1) sd += __shfl_xor(sd, off, 64);
  sd *= 0.125f;

  // --- 32 candidate keys, 2 lanes per key (half = 32 dims each) ---
  const int c = lane >> 1, half = lane & 1;
  int j, valid;
  if (c < 16) {
    j = i - NHWIN + c;  // window j = i-16 .. i-1
    valid = (j >= 0);
  } else {
    const int* rr = rand_idx + ((size_t)b * NS + iv) * NRC;
    const int cr = c - 16;
    j = rr[cr];
    valid = (j <= i - NHWIN - 1);  // causal AND strictly below window
    for (int cp = 0; cp < cr; cp++) valid &= (rr[cp] != j);  // first occurrence wins
  }
  const int jr = valid ? j : 0;
  float s = 0.f;
  {
    const u16* krow = kbase + (size_t)jr * NHD + half * 32;
    for (int c8 = 0; c8 < 4; c8++) {
      bf16x8 kv = *(const bf16x8*)(krow + c8 * 8);
      bf16x8 qv = *(const bf16x8*)(&ql[wave][half * 32 + c8 * 8]);
      for (int e = 0; e < 8; e++) s += bf2f(qv[e]) * bf2f(kv[e]);
    }
  }
  s += __shfl_xor(s, 1, 64);  // combine halves; both lanes of pair hold full dot
  s = valid ? s * 0.125f : -INFINITY;

  // --- softmax over {32 candidates} U {diag} ---
  float smax = s;
  for (int off = 1; off < 64; off <<= 1) smax = fmaxf(smax, __shfl_xor(smax, off, 64));
  smax = fmaxf(smax, sd);
  float p = valid ? __expf(s - smax) : 0.f;
  float pd = __expf(sd - smax);
  float pm = (half == 0) ? p : 0.f;
  for (int off = 1; off < 64; off <<= 1) pm += __shfl_xor(pm, off, 64);
  const float lsum = pm + pd;

  if (half == 0) {
    pl[wave][c] = p;
    jl[wave][c] = jr;
  }
  if (lane == 0) {
    pl[wave][32] = pd;
    jl[wave][32] = iv;
  }
  __syncthreads();

  // --- PV: lane = output dim; key index is wave-uniform -> SGPR base via readfirstlane ---
  float o = 0.f;
  for (int jj = 0; jj < 33; jj++) {
    const int jk = __builtin_amdgcn_readfirstlane(jl[wave][jj]);
    const float pj = pl[wave][jj];
    o += pj * bf2f((short)vbase[(size_t)jk * NHD + lane]);
  }
  if (i >= 0)
    attnb[((size_t)(b * NS + i) * NH + h) * NHD + lane] = f2bf(o / lsum);
}

extern "C" void kernel_launch(void* const* d_in, const int* in_sizes, int n_in,
                              void* d_out, int out_size, void* d_ws, size_t ws_size,
                              hipStream_t stream) {
  const float* x = (const float*)d_in[0];
  const float* bq = (const float*)d_in[2];
  const float* bk = (const float*)d_in[4];
  const float* bv = (const float*)d_in[6];
  const float* bo = (const float*)d_in[8];
  const float* Ws1 = (const float*)d_in[9];
  const float* bs1 = (const float*)d_in[10];
  const float* Ws2 = (const float*)d_in[11];
  const int* rand_idx = (const int*)d_in[13];
  float* out = (float*)d_out;

  // workspace layout (~33 MB)
  char* p = (char*)d_ws;
  u16* wt = (u16*)p;         p += (size_t)4 * ND * ND * 2;         // 2 MB  [Wq^T;Wk^T;Wv^T;Wo^T] bf16
  u16* qbuf = (u16*)p;       p += (size_t)NB * NH * NS * NHD * 2;  // 4 MB [B,H,S,HD]
  u16* kbuf = (u16*)p;       p += (size_t)NB * NH * NS * NHD * 2;  // 4 MB
  u16* vtbuf = (u16*)p;      p += (size_t)NB * NH * NHD * NS * 2;  // 4 MB [B,H,HD,S]
  u16* vbuf = (u16*)p;       p += (size_t)NB * NH * NS * NHD * 2;  // 4 MB [B,H,S,HD]
  u16* attnb = (u16*)p;      p += (size_t)NB * NS * ND * 2;        // 4 MB [B,S,H,HD]
  float* part = (float*)p;   p += (size_t)NB * NS * 4 * 4;         // 64 KB logit partials
  int* rowimp = (int*)p;     p += (size_t)NB * NS * 4;
  int* ilist = (int*)p;      p += (size_t)NB * NILIST * 4;
  int* nlist = (int*)p;      p += (size_t)NB * NSPAD * 4;
  float* pbuf = (float*)p;   // 10.8 MB partials

  csa_cvt_w<<<dim3(8, 16, 4), 256, 0, stream>>>((const float*)d_in[1], (const float*)d_in[3],
                                                (const float*)d_in[5], (const float*)d_in[7], wt);

  // scorer (fp32 exact ranking; sigmoid/bs2 dropped - rank-monotone; no atomics)
  csa_scorer<<<dim3(NB * NS / 64, 4), 256, 0, stream>>>(x, Ws1, bs1, Ws2, part);
  csa_rank<<<dim3(NS / 8, NB), 256, 0, stream>>>(part, rowimp);
  csa_ilist<<<dim3(NB), 256, 0, stream>>>(rowimp, ilist, nlist);

  // fused QKV projection (reads fp32 x directly)
  csa_gemm_qkv<<<dim3(32, 24), 256, 0, stream>>>(x, wt, bq, bk, bv, qbuf, kbuf, vtbuf, vbuf);

  // attention: important rows (MFMA, 8-way split-K, 64-key tiles) + sparse rows (per-wave)
  csa_attn_imp<<<dim3(NILIST / 16, NCHUNK, NB * NH), 64, 0, stream>>>(qbuf, kbuf, vtbuf, ilist, pbuf);
  csa_attn_sparse<<<dim3(NSPAD / 4, NH, NB), 256, 0, stream>>>(qbuf, kbuf, vbuf, nlist, rand_idx, attnb);
  csa_merge<<<dim3(NKTOP, NH, NB), 64, 0, stream>>>(pbuf, ilist, attnb);

  // output projection
  csa_gemm_out<<<dim3(64, 8), 256, 0, stream>>>(attnb, wt + 3 * (size_t)ND * ND, bo, out);
}